// Round 8
// baseline (608.225 us; speedup 1.0000x reference)
//
#include <hip/hip_runtime.h>
#include <hip/hip_bf16.h>
#include <math.h>

#define NH 8
#define DKk 256
#define DVv 512
#define Bn 2
#define Tn 2048
#define HID 2048
#define EPSf 1e-5f

typedef __bf16 bf16x8 __attribute__((ext_vector_type(8)));
typedef float f32x4 __attribute__((ext_vector_type(4)));
typedef unsigned short us8 __attribute__((ext_vector_type(8)));
using bf16 = __hip_bfloat16;
typedef unsigned short ushort_t;

__device__ __forceinline__ void gload_lds16(const void* g, void* lds_base) {
  __builtin_amdgcn_global_load_lds(
      (const __attribute__((address_space(1))) void*)g,
      (__attribute__((address_space(3))) void*)lds_base, 16, 0, 0);
}

__device__ __forceinline__ ushort_t f2bf_raw(float f) {
  bf16 h = __float2bfloat16(f);
  return *reinterpret_cast<ushort_t*>(&h);
}
__device__ __forceinline__ float bf2f_raw(ushort_t u) {
  union { unsigned int i; float f; } v; v.i = ((unsigned int)u) << 16; return v.f;
}

// ---------------- fp32 -> bf16 elementwise (vectorized x4) ----------------
__global__ void k_f32_to_bf16(const float4* __restrict__ in, ushort4* __restrict__ out, int n4) {
  int i = blockIdx.x * blockDim.x + threadIdx.x;
  if (i >= n4) return;
  float4 v = in[i];
  ushort4 o;
  o.x = f2bf_raw(v.x); o.y = f2bf_raw(v.y); o.z = f2bf_raw(v.z); o.w = f2bf_raw(v.w);
  out[i] = o;
}

// ---------------- fp32 a + b -> out (vectorized x4), split-K reduce ----------------
__global__ void k_add2_f32(const float4* __restrict__ a, const float4* __restrict__ b,
                           float4* __restrict__ o, int n4) {
  int i = blockIdx.x * blockDim.x + threadIdx.x;
  if (i >= n4) return;
  float4 x = a[i], y = b[i];
  float4 r; r.x = x.x + y.x; r.y = x.y + y.y; r.z = x.z + y.z; r.w = x.w + y.w;
  o[i] = r;
}

// ---------------- W (K,N) fp32 -> WT (N,K) bf16 ----------------
__global__ void k_transpose_w(const float* __restrict__ W, bf16* __restrict__ WT, int K, int N) {
  __shared__ float t[32][33];
  int n0 = blockIdx.x * 32, k0 = blockIdx.y * 32;
  int tx = threadIdx.x, ty = threadIdx.y;
#pragma unroll
  for (int i = 0; i < 4; i++)
    t[ty + i * 8][tx] = W[(size_t)(k0 + ty + i * 8) * N + n0 + tx];
  __syncthreads();
#pragma unroll
  for (int i = 0; i < 4; i++)
    WT[(size_t)(n0 + ty + i * 8) * K + k0 + tx] = __float2bfloat16(t[tx][ty + i * 8]);
}

// ---------------- v (b,t,h,dv) bf16 -> vS[bh][kt][chunk(4)][dv(512)] 16B units ----------------
__global__ void k_build_vS(const ushort_t* __restrict__ v, ushort_t* __restrict__ vS) {
  __shared__ ushort_t t[32 * 520];
  const int tid = threadIdx.x;
  const int kt = blockIdx.x;
  const int bh = blockIdx.y;
  const int b = bh >> 3, h = bh & 7;
#pragma unroll
  for (int r = 0; r < 8; r++) {
    int j = r * 4 + (tid >> 6);
    int vec = tid & 63;
    us8 d = *(const us8*)(v + (((size_t)(b * Tn + kt * 32 + j) * NH + h) * DVv) + vec * 8);
    *(us8*)(&t[j * 520 + vec * 8]) = d;
  }
  __syncthreads();
#pragma unroll
  for (int u = 0; u < 8; u++) {
    int uid = u * 256 + tid;
    int chunk = uid >> 9;
    int dv = uid & 511;
    us8 o;
#pragma unroll
    for (int jj = 0; jj < 8; jj++) o[jj] = t[(chunk * 8 + jj) * 520 + dv];
    *(us8*)(vS + ((size_t)(bh * 64 + kt) * 2048 + chunk * 512 + dv) * 8) = o;
  }
}

// ---------------- RoPE in-place on bf16 (b,t,h,dk), scale folded ----------------
__global__ void k_rope(bf16* __restrict__ x, float scale) {
  int tid = blockIdx.x * 256 + threadIdx.x;
  int i = tid & 127;
  int h = (tid >> 7) & 7;
  int t = (tid >> 10) & (Tn - 1);
  int b = tid >> 21;
  float inv = exp2f(-(float)i * (13.287712379549449f / 128.0f));
  float ang = (float)t * inv;
  float s, c;
  sincosf(ang, &s, &c);
  size_t base = ((size_t)(b * Tn + t) * NH + h) * DKk + i;
  float x1 = __bfloat162float(x[base]);
  float x2 = __bfloat162float(x[base + 128]);
  x[base]       = __float2bfloat16((x1 * c - x2 * s) * scale);
  x[base + 128] = __float2bfloat16((x2 * c + x1 * s) * scale);
}

// ================= 256x256 8-phase GEMM, v5: deep-slack stages (>=3-4 phases every link) ====
// Reads (unchanged from R5-verified v3): ph1 A0-3+B01, ph2 A4-7, ph3 B23 per buffer;
// quadrants Q00,Q10,Q01,Q11. Stage layout moved into earliest region-free slots:
//   ph3: A(t+2)h0        ph4: A(t+2)h1 + B(t+2)h0     ph5: B(t+2)h1
//   ph7: A(t+3)h0        ph8: A(t+3)h1 + B(t+3)h0 + B(t+3)h1
// Waits: vmcnt(6) end-ph4 (14 outstanding -> drains exactly A(t+1)+B(t+1));
//        vmcnt(8) end-ph8 (16 outstanding -> drains exactly A(t+2)+B(t+2)).
// Slack: every stage->wait link >= 3-4 phases (was 2 for B). Region ledger (verified):
// buf0.A free after ph2 drain -> ph3/4; buf0.B free after ph3 drain -> ph4/5;
// buf1.A free after ph6 drain -> ph7/8; buf1.B free after ph7 drain -> ph8.
// Prologue: 16 loads [A0,B0,A1,B1]; vmcnt(8) leaves tile1's 8 = steady entry state.
// Last iter: no stages; entry 8 all belong to t+1 -> VMW0 at ph4.
// DO NOT add counted-lgkm read-ahead (R6: regression). Split-K via blockIdx.z (F32S partials).
#define BARX() asm volatile("s_barrier" ::: "memory")
#define LGKM0() { asm volatile("s_waitcnt lgkmcnt(0)" ::: "memory"); __builtin_amdgcn_sched_barrier(0); }
#define VMW6() asm volatile("s_waitcnt vmcnt(6)" ::: "memory")
#define VMW8() asm volatile("s_waitcnt vmcnt(8)" ::: "memory")
#define VMW0() asm volatile("s_waitcnt vmcnt(0)" ::: "memory")
#define PRIO1 __builtin_amdgcn_s_setprio(1)
#define PRIO0 __builtin_amdgcn_s_setprio(0)

#define QUADQ(MB, NB)                                                              \
  { _Pragma("unroll") for (int kk_ = 0; kk_ < 2; ++kk_)                            \
    _Pragma("unroll") for (int mf_ = 0; mf_ < 4; ++mf_)                            \
    _Pragma("unroll") for (int nf_ = 0; nf_ < 2; ++nf_)                            \
      acc[(MB) + mf_][(NB) + nf_] = __builtin_amdgcn_mfma_f32_16x16x32_bf16(       \
          ar[(MB) + mf_][kk_], br[(NB) + nf_][kk_],                                \
          acc[(MB) + mf_][(NB) + nf_], 0, 0, 0); }

template <bool F32S>
__global__ __launch_bounds__(512, 2) void k_gemm8(const bf16* __restrict__ A, const bf16* __restrict__ BT,
                                                  void* __restrict__ O0, void* __restrict__ O1,
                                                  int nsplit, int M, int Ntot, int Kloop, int Kstride) {
  extern __shared__ char lds[];
  const int tid = threadIdx.x;
  const int lane = tid & 63;
  const int w = tid >> 6;        // 0..7
  const int wr = w >> 2;         // 0..1 (M half)
  const int wc = w & 3;          // 0..3 (N quarter)
  const int quad = lane >> 4, c16 = lane & 15;
  const int m0 = blockIdx.y * 256, n0 = blockIdx.x * 256;
  const int ks = blockIdx.z;

  const bf16* Ab = A + (size_t)ks * Kloop;
  const bf16* Bb = BT + (size_t)ks * Kloop;

  const int srow = (w << 4) | (lane >> 3);
  const int gsw = (((lane & 7) ^ (lane >> 3)) << 4);   // inverse-swizzled source granule
  const size_t rowBytes = (size_t)Kstride * 2;
  const char* aS = (const char*)(Ab + (size_t)(m0 + srow) * Kstride) + gsw;
  const char* bS = (const char*)(Bb + (size_t)(n0 + srow) * Kstride) + gsw;

  auto stage = [&](int matB, int buf, int h, int t) {
    const char* base = (matB ? bS : aS) + (size_t)h * 128 * rowBytes + (size_t)t * 128;
    char* ldst = lds + buf * 65536 + matB * 32768 + h * 16384 + w * 2048;
    gload_lds16(base, ldst);
    gload_lds16(base + 8 * rowBytes, ldst + 1024);
  };
  auto ldA = [&](int buf, int mf, int kk) -> bf16x8 {
    int row = wr * 128 + mf * 16 + c16;
    return *(const bf16x8*)(lds + buf * 65536 + row * 128 + ((((kk << 2) | quad) ^ (c16 & 7)) << 4));
  };
  auto ldB = [&](int buf, int nf, int kk) -> bf16x8 {
    int row = wc * 64 + nf * 16 + c16;
    return *(const bf16x8*)(lds + buf * 65536 + 32768 + row * 128 + ((((kk << 2) | quad) ^ (c16 & 7)) << 4));
  };

  f32x4 acc[8][4];
  const f32x4 fz = {0.f, 0.f, 0.f, 0.f};
#pragma unroll
  for (int i = 0; i < 8; i++)
#pragma unroll
    for (int j = 0; j < 4; j++) acc[i][j] = fz;
  bf16x8 ar[8][2], br[4][2];

  const int nT = Kloop >> 6;
  const int nIter = nT >> 1;

  // prologue: tiles 0,1 fully staged in order [A0, B0, A1, B1] (16 loads);
  // vmcnt(8) drains tile0, leaves tile1's [Ah0,Ah1,Bh0,Bh1] = steady-state entry.
  stage(0, 0, 0, 0); stage(0, 0, 1, 0);
  stage(1, 0, 0, 0); stage(1, 0, 1, 0);
  stage(0, 1, 0, 1); stage(0, 1, 1, 1);
  stage(1, 1, 0, 1); stage(1, 1, 1, 1);
  VMW8();
  BARX();

  for (int it = 0; it < nIter; ++it) {
    const int t = it * 2;
    const bool last = (it == nIter - 1);
    // ---- ph1: ds A0-3 + B01 (buf0); Q00 ----
#pragma unroll
    for (int mf = 0; mf < 4; ++mf) { ar[mf][0] = ldA(0, mf, 0); ar[mf][1] = ldA(0, mf, 1); }
#pragma unroll
    for (int nf = 0; nf < 2; ++nf) { br[nf][0] = ldB(0, nf, 0); br[nf][1] = ldB(0, nf, 1); }
    BARX(); LGKM0();
    PRIO1; QUADQ(0, 0); PRIO0;
    BARX();
    // ---- ph2: ds A4-7 (buf0); Q10 ----
#pragma unroll
    for (int mf = 4; mf < 8; ++mf) { ar[mf][0] = ldA(0, mf, 0); ar[mf][1] = ldA(0, mf, 1); }
    BARX(); LGKM0();
    PRIO1; QUADQ(4, 0); PRIO0;
    BARX();
    // ---- ph3: ds B23 (buf0); stage A(t+2)h0; Q01 ----
#pragma unroll
    for (int nf = 2; nf < 4; ++nf) { br[nf][0] = ldB(0, nf, 0); br[nf][1] = ldB(0, nf, 1); }
    if (!last) stage(0, 0, 0, t + 2);
    BARX(); LGKM0();
    PRIO1; QUADQ(0, 2); PRIO0;
    BARX();
    // ---- ph4: stage A(t+2)h1 + B(t+2)h0; Q11; vmcnt(6) -> tile t+1 landed ----
    if (!last) { stage(0, 0, 1, t + 2); stage(1, 0, 0, t + 2); }
    BARX();
    PRIO1; QUADQ(4, 2); PRIO0;
    if (!last) { VMW6(); } else { VMW0(); }
    BARX();
    // ---- ph5: ds A0-3 + B01 (buf1); stage B(t+2)h1; Q00 ----
#pragma unroll
    for (int mf = 0; mf < 4; ++mf) { ar[mf][0] = ldA(1, mf, 0); ar[mf][1] = ldA(1, mf, 1); }
#pragma unroll
    for (int nf = 0; nf < 2; ++nf) { br[nf][0] = ldB(1, nf, 0); br[nf][1] = ldB(1, nf, 1); }
    if (!last) stage(1, 0, 1, t + 2);
    BARX(); LGKM0();
    PRIO1; QUADQ(0, 0); PRIO0;
    BARX();
    // ---- ph6: ds A4-7 (buf1); Q10 ----
#pragma unroll
    for (int mf = 4; mf < 8; ++mf) { ar[mf][0] = ldA(1, mf, 0); ar[mf][1] = ldA(1, mf, 1); }
    BARX(); LGKM0();
    PRIO1; QUADQ(4, 0); PRIO0;
    BARX();
    // ---- ph7: ds B23 (buf1); stage A(t+3)h0; Q01 ----
#pragma unroll
    for (int nf = 2; nf < 4; ++nf) { br[nf][0] = ldB(1, nf, 0); br[nf][1] = ldB(1, nf, 1); }
    if (!last) stage(0, 1, 0, t + 3);
    BARX(); LGKM0();
    PRIO1; QUADQ(0, 2); PRIO0;
    BARX();
    // ---- ph8: stage A(t+3)h1 + B(t+3)h0 + B(t+3)h1; Q11; vmcnt(8) -> tile t+2 landed ----
    if (!last) { stage(0, 1, 1, t + 3); stage(1, 1, 0, t + 3); stage(1, 1, 1, t + 3); }
    BARX();
    PRIO1; QUADQ(4, 2); PRIO0;
    if (!last) VMW8();
    BARX();
  }

  if (F32S) {
    // split-K fp32 partial: z selects buffer, full N width
    float* Ob = (float*)(ks ? O1 : O0);
#pragma unroll
    for (int mf = 0; mf < 8; ++mf)
#pragma unroll
      for (int nf = 0; nf < 4; ++nf)
#pragma unroll
        for (int rr = 0; rr < 4; ++rr) {
          int m = m0 + wr * 128 + mf * 16 + quad * 4 + rr;
          int n = n0 + wc * 64 + nf * 16 + c16;
          Ob[(size_t)m * Ntot + n] = acc[mf][nf][rr];
        }
  } else {
    // dual bf16 outputs split at n = nsplit
    bf16* Ob; int ldo, nc0;
    if (n0 < nsplit) { Ob = (bf16*)O0; ldo = nsplit; nc0 = n0; }
    else             { Ob = (bf16*)O1; ldo = Ntot - nsplit; nc0 = n0 - nsplit; }
#pragma unroll
    for (int mf = 0; mf < 8; ++mf)
#pragma unroll
      for (int nf = 0; nf < 4; ++nf)
#pragma unroll
        for (int rr = 0; rr < 4; ++rr) {
          int m = m0 + wr * 128 + mf * 16 + quad * 4 + rr;
          int n = nc0 + wc * 64 + nf * 16 + c16;
          Ob[(size_t)m * ldo + n] = __float2bfloat16(acc[mf][nf][rr]);
        }
  }
}

// ---------------- Retention v4 (R5/R7-measured best): rotated loop {PV(t-1); S(t)} ----------------
// K-dbuf + V-sbuf + P-dbuf, LDS 76.8KB -> 2 blocks/CU + counted-vmcnt pipelining.
// Ledger verified in R4/R5. (v5 swapped-S + shfl redistribute regressed in R6 — do not reapply.)
__global__ __launch_bounds__(256, 2) void k_retention(const bf16* __restrict__ q, const bf16* __restrict__ k,
                                                      const char* __restrict__ vS, const bf16* __restrict__ g,
                                                      const float* __restrict__ gnw, bf16* __restrict__ X) {
  extern __shared__ char smem[];
  ushort_t* p_lds_base = (ushort_t*)(smem + 65536);
  float* red = (float*)(smem + 75776);
  bf16* o_lds = (bf16*)smem;   // epilogue alias (64KB)

  const int tid = threadIdx.x;
  const int l = tid & 63, w = tid >> 6;
  const int quad = l >> 4, c16 = l & 15;

  const int bid = blockIdx.x;
  const int u = (bid & 255) >> 4;
  const int qt = (bid < 256) ? (31 - u) : u;   // heavy half then light half
  const int bh = bid & 15;
  const int b = bh >> 3, h = bh & 7;
  const int q0 = qt * 64;

  bf16x8 qf[8];
  {
    const bf16* qrow = q + ((size_t)(b * Tn + q0 + w * 16 + c16) * NH + h) * DKk + quad * 8;
#pragma unroll
    for (int c = 0; c < 8; c++) qf[c] = *(const bf16x8*)(qrow + c * 32);
  }

  const float log2g = log2f(1.0f - exp2f(-5.0f - (float)h));

  f32x4 acc[4][8];
  const f32x4 fz = {0.f, 0.f, 0.f, 0.f};
#pragma unroll
  for (int rt = 0; rt < 4; rt++)
#pragma unroll
    for (int n = 0; n < 8; n++) acc[rt][n] = fz;

  const int ktmax = 2 * qt + 1;
  const float Dcut = 30.0f / (-log2g);
  int kt0 = (int)fmaxf(0.0f, floorf(((float)q0 - Dcut) * (1.0f / 32.0f)));

  const char* vS_tilebase = vS + (size_t)(bh * 64) * 32768;

  auto stageK = [&](int kt) {
    const int pb = (kt - kt0) & 1;
#pragma unroll
    for (int i = 0; i < 4; i++) {
      int instr = w * 4 + i;
      int j = instr * 2 + (l >> 5);
      int cg = (l & 31) ^ (j & 7);
      const char* gp = (const char*)(k + ((size_t)(b * Tn + kt * 32 + j) * NH + h) * DKk) + cg * 16;
      gload_lds16(gp, smem + pb * 16384 + instr * 1024);
    }
  };
  auto stageV = [&](int kt) {
#pragma unroll
    for (int i = 0; i < 8; i++) {
      int instr = w * 8 + i;
      const char* gp = vS_tilebase + (size_t)kt * 32768 + instr * 1024 + l * 16;
      gload_lds16(gp, smem + 32768 + instr * 1024);
    }
  };

  auto S_phase = [&](int kt) {
    const int pb = (kt - kt0) & 1;
    f32x4 sacc[2] = {fz, fz};
#pragma unroll
    for (int jt = 0; jt < 2; jt++)
#pragma unroll
      for (int c = 0; c < 8; c++) {
        const char* kp = smem + pb * 16384 + (jt * 16 + c16) * 512 + (((c * 4 + quad) ^ (c16 & 7)) * 16);
        bf16x8 bfrag = *(const bf16x8*)kp;
        sacc[jt] = __builtin_amdgcn_mfma_f32_16x16x32_bf16(qf[c], bfrag, sacc[jt], 0, 0, 0);
      }
    ushort_t* pbuf = p_lds_base + pb * 2560;
#pragma unroll
    for (int jt = 0; jt < 2; jt++)
#pragma unroll
      for (int r = 0; r < 4; r++) {
        int ig = q0 + w * 16 + quad * 4 + r;
        int jg = kt * 32 + jt * 16 + c16;
        int d = ig - jg;
        float val = (d >= 0) ? sacc[jt][r] * exp2f(log2g * (float)d) : 0.0f;
        pbuf[(w * 16 + quad * 4 + r) * 40 + jt * 16 + c16] = f2bf_raw(val);
      }
  };

  auto PV_phase = [&](int kt) {
    const int pb = (kt - kt0) & 1;
    const char* pbuf = (const char*)(p_lds_base + pb * 2560);
    bf16x8 pa[4];
#pragma unroll
    for (int rt = 0; rt < 4; rt++)
      pa[rt] = *(const bf16x8*)(pbuf + (rt * 16 + c16) * 80 + quad * 16);
    const char* v_lds = smem + 32768;
#pragma unroll
    for (int n = 0; n < 8; n++) {
      bf16x8 bv = *(const bf16x8*)(v_lds + quad * 8192 + (w * 128 + n * 16 + c16) * 16);
#pragma unroll
      for (int rt = 0; rt < 4; rt++)
        acc[rt][n] = __builtin_amdgcn_mfma_f32_16x16x32_bf16(pa[rt], bv, acc[rt][n], 0, 0, 0);
    }
  };

#define SBARR() { __builtin_amdgcn_sched_barrier(0); __builtin_amdgcn_s_barrier(); }
#define WLGKM0() { asm volatile("s_waitcnt lgkmcnt(0)" ::: "memory"); }

  // ---- peeled first iteration (S-only) ----
  stageK(kt0);                                        // out: K(kt0)(4)  [+qf(8) older]
  stageV(kt0);                                        // out: +V(kt0)(8)
  asm volatile("s_waitcnt vmcnt(8)" ::: "memory");    // drains qf + K(kt0); V(kt0) flies
  SBARR();
  S_phase(kt0);
  if (kt0 + 1 <= ktmax) stageK(kt0 + 1);              // out: V(kt0)(8), K(kt0+1)(4)
  WLGKM0(); SBARR();

  // ---- main loop ----
  for (int kt = kt0 + 1; kt <= ktmax; ++kt) {
    asm volatile("s_waitcnt vmcnt(4)" ::: "memory");  // V(kt-1) landed; K(kt) flies
    SBARR();
    PV_phase(kt - 1);
    WLGKM0(); SBARR();                                // V buf + p[kt-1] free
    stageV(kt);                                       // out: K(kt)(4), V(kt)(8)
    asm volatile("s_waitcnt vmcnt(8)" ::: "memory");  // K(kt) landed; V(kt) flies
    SBARR();
    S_phase(kt);
    if (kt + 1 <= ktmax) stageK(kt + 1);              // out: V(kt)(8), K(kt+1)(4)
    WLGKM0(); SBARR();                                // p[kt] visible
  }

  // ---- epilogue PV(ktmax) ----
  asm volatile("s_waitcnt vmcnt(0)" ::: "memory");
  SBARR();
  PV_phase(ktmax);

  // RMS: wave has 128-dv partial for all 64 rows -> cross-wave combine via red
  __syncthreads();
#pragma unroll
  for (int rt = 0; rt < 4; rt++)
#pragma unroll
    for (int r = 0; r < 4; r++) {
      float s = 0.f;
#pragma unroll
      for (int n = 0; n < 8; n++) { float v = acc[rt][n][r]; s += v * v; }
      s += __shfl_xor(s, 1);
      s += __shfl_xor(s, 2);
      s += __shfl_xor(s, 4);
      s += __shfl_xor(s, 8);
      if (c16 == 0) red[(rt * 16 + quad * 4 + r) * 4 + w] = s;
    }
  __syncthreads();
  float ss[4][4];
#pragma unroll
  for (int rt = 0; rt < 4; rt++)
#pragma unroll
    for (int r = 0; r < 4; r++) {
      int row = rt * 16 + quad * 4 + r;
      float tot = red[row * 4] + red[row * 4 + 1] + red[row * 4 + 2] + red[row * 4 + 3];
      ss[rt][r] = rsqrtf(tot * (1.0f / DVv) + EPSf);
    }
  __syncthreads();

#pragma unroll
  for (int n = 0; n < 8; n++) {
    int col = w * 128 + n * 16 + c16;
    float gw = gnw[col];
#pragma unroll
    for (int rt = 0; rt < 4; rt++)
#pragma unroll
      for (int r = 0; r < 4; r++) {
        int row = rt * 16 + quad * 4 + r;
        o_lds[row * 512 + col] = __float2bfloat16(acc[rt][n][r] * ss[rt][r] * gw);
      }
  }
  __syncthreads();

#pragma unroll
  for (int it = 0; it < 16; it++) {
    int cid = it * 256 + tid;
    int row = cid >> 6;
    int cp = (cid & 63) * 8;
    const ushort_t* gp = (const ushort_t*)g + ((size_t)(b * Tn + q0 + row) * NH + h) * DVv + cp;
    us8 gv = *(const us8*)gp;
    us8 ov;
#pragma unroll
    for (int e = 0; e < 8; e++) {
      float gf = bf2f_raw(gv[e]);
      float gate = gf / (1.0f + expf(-gf));
      float of = __bfloat162float(o_lds[row * 512 + cp + e]);
      ov[e] = f2bf_raw(of * gate);
    }
    *(us8*)((ushort_t*)X + ((size_t)(b * Tn + q0 + row) * NH + h) * DVv + cp) = ov;
  }
}

extern "C" void kernel_launch(void* const* d_in, const int* in_sizes, int n_in,
                              void* d_out, int out_size, void* d_ws, size_t ws_size,
                              hipStream_t stream) {
  const float* hs  = (const float*)d_in[0];
  const float* Wq  = (const float*)d_in[1];
  const float* Wk  = (const float*)d_in[2];
  const float* Wv  = (const float*)d_in[3];
  const float* Wg  = (const float*)d_in[4];
  const float* Wo  = (const float*)d_in[5];
  const float* gnw = (const float*)d_in[6];
  float* out = (float*)d_out;
  char* ws = (char*)d_ws;

  bf16* hsb = (bf16*)(ws);                    // 16 MB
  bf16* WqT = (bf16*)(ws + 16777216);         //  8 MB  } contiguous [4096][2048] for fused qk
  bf16* WkT = (bf16*)(ws + 25165824);         //  8 MB  }
  bf16* WvT = (bf16*)(ws + 33554432);         // 16 MB  } contiguous [8192][2048] for fused vg
  bf16* WgT = (bf16*)(ws + 50331648);         // 16 MB  }
  char* vSb = ws;                              // alias hsb/WqT/WkT (dead after q/k/v/g GEMMs)
  bf16* WoT = (bf16*)(ws + 33554432);         // alias WvT (dead after vg GEMM)
  bf16* qb = (bf16*)(ws + 67108864);          // 16 MB
  bf16* kb = (bf16*)(ws + 83886080);          // 16 MB
  bf16* vb = (bf16*)(ws + 100663296);         // 32 MB
  bf16* gb = (bf16*)(ws + 134217728);         // 32 MB
  bf16* Xb = vb;                               // alias v (dead after vS build)
  float* p0 = (float*)ws;                      // 32 MB fp32 partial (alias vSb, dead after retention)
  float* p1 = (float*)(ws + 50331648);         // 32 MB fp32 partial (alias WgT+qb, dead after retention)

  static bool attr_done = false;
  if (!attr_done) {
    hipFuncSetAttribute((const void*)k_gemm8<false>, hipFuncAttributeMaxDynamicSharedMemorySize, 131072);
    hipFuncSetAttribute((const void*)k_gemm8<true>, hipFuncAttributeMaxDynamicSharedMemorySize, 131072);
    hipFuncSetAttribute((const void*)k_retention, hipFuncAttributeMaxDynamicSharedMemorySize, 76800);
    attr_done = true;
  }

  dim3 tb(32, 8);

  k_f32_to_bf16<<<8192, 256, 0, stream>>>((const float4*)hs, (ushort4*)hsb, 2097152);
  k_transpose_w<<<dim3(HID / 32, HID / 32), tb, 0, stream>>>(Wq, WqT, HID, HID);
  k_transpose_w<<<dim3(HID / 32, HID / 32), tb, 0, stream>>>(Wk, WkT, HID, HID);
  k_transpose_w<<<dim3(NH * DVv / 32, HID / 32), tb, 0, stream>>>(Wv, WvT, HID, NH * DVv);
  k_transpose_w<<<dim3(NH * DVv / 32, HID / 32), tb, 0, stream>>>(Wg, WgT, HID, NH * DVv);
  // fused q|k: C[4096][4096] = hsb @ [WqT|WkT]^T, split at n=2048 -> qb, kb
  k_gemm8<false><<<dim3(16, 16), 512, 131072, stream>>>(hsb, WqT, qb, kb, 2048, 4096, 4096, 2048, 2048);
  // fused v|g: C[4096][8192] = hsb @ [WvT|WgT]^T, split at n=4096 -> vb, gb
  k_gemm8<false><<<dim3(32, 16), 512, 131072, stream>>>(hsb, WvT, vb, gb, 4096, 4096, 8192, 2048, 2048);
  k_rope<<<16384, 256, 0, stream>>>(qb, 0.0625f);
  k_rope<<<16384, 256, 0, stream>>>(kb, 1.0f);
  k_build_vS<<<dim3(64, 16), 256, 0, stream>>>((const ushort_t*)vb, (ushort_t*)vSb);
  k_transpose_w<<<dim3(HID / 32, NH * DVv / 32), tb, 0, stream>>>(Wo, WoT, NH * DVv, HID);
  k_retention<<<512, 256, 76800, stream>>>(qb, kb, vSb, gb, gnw, Xb);
  // out-proj split-K=2 through the 8-phase kernel: 256 blocks (full GPU), fp32 partials + reduce
  k_gemm8<true><<<dim3(8, 16, 2), 512, 131072, stream>>>(Xb, WoT, p0, p1, 2048, 4096, 2048, 2048, 4096);
  k_add2_f32<<<8192, 256, 0, stream>>>((const float4*)p0, (const float4*)p1, (float4*)out, 2097152);
}

// Round 9
// 605.892 us; speedup vs baseline: 1.0039x; 1.0039x over previous
//
#include <hip/hip_runtime.h>
#include <hip/hip_bf16.h>
#include <math.h>

#define NH 8
#define DKk 256
#define DVv 512
#define Bn 2
#define Tn 2048
#define HID 2048
#define EPSf 1e-5f

typedef __bf16 bf16x8 __attribute__((ext_vector_type(8)));
typedef float f32x4 __attribute__((ext_vector_type(4)));
typedef unsigned short us8 __attribute__((ext_vector_type(8)));
using bf16 = __hip_bfloat16;
typedef unsigned short ushort_t;

__device__ __forceinline__ void gload_lds16(const void* g, void* lds_base) {
  __builtin_amdgcn_global_load_lds(
      (const __attribute__((address_space(1))) void*)g,
      (__attribute__((address_space(3))) void*)lds_base, 16, 0, 0);
}

__device__ __forceinline__ ushort_t f2bf_raw(float f) {
  bf16 h = __float2bfloat16(f);
  return *reinterpret_cast<ushort_t*>(&h);
}
__device__ __forceinline__ float bf2f_raw(ushort_t u) {
  union { unsigned int i; float f; } v; v.i = ((unsigned int)u) << 16; return v.f;
}

// ---------------- fp32 -> bf16 elementwise (vectorized x4) ----------------
__global__ void k_f32_to_bf16(const float4* __restrict__ in, ushort4* __restrict__ out, int n4) {
  int i = blockIdx.x * blockDim.x + threadIdx.x;
  if (i >= n4) return;
  float4 v = in[i];
  ushort4 o;
  o.x = f2bf_raw(v.x); o.y = f2bf_raw(v.y); o.z = f2bf_raw(v.z); o.w = f2bf_raw(v.w);
  out[i] = o;
}

// ---------------- fp32 a + b -> out (vectorized x4), split-K reduce ----------------
__global__ void k_add2_f32(const float4* __restrict__ a, const float4* __restrict__ b,
                           float4* __restrict__ o, int n4) {
  int i = blockIdx.x * blockDim.x + threadIdx.x;
  if (i >= n4) return;
  float4 x = a[i], y = b[i];
  float4 r; r.x = x.x + y.x; r.y = x.y + y.y; r.z = x.z + y.z; r.w = x.w + y.w;
  o[i] = r;
}

// ---------------- W (K,N) fp32 -> WT (N,K) bf16, 64x64 tile, BW-optimal ----------------
// Per thread: read 2 rows x 8 cols via 4x float4 (64B); pack row-pair into u32
// {bf16(k even) | bf16(k odd)<<16}; 8 LDS u32 writes at odd stride 33 (bank = (8b+a+j)%32,
// exact 2-way alias = free). Phase 2: thread (n=t>>2, part=t&3) reads 8 contiguous u32 =
// k = part*16..+15 (little-endian gives bf16 order k,k+1) and stores 2x uint4 = 32B/lane.
// Replaces k_transpose_w (2B/lane writes, ~1-1.5 TB/s) — G13: always vectorize stores.
__global__ __launch_bounds__(256) void k_transpose64(const float* __restrict__ W, bf16* __restrict__ WT,
                                                     int K, int N) {
  __shared__ unsigned int t32[64 * 33];  // 8448 B
  const int tid = threadIdx.x;
  const int n0 = blockIdx.x * 64, k0 = blockIdx.y * 64;
  const int a = tid >> 3;    // 0..31 row-pair
  const int bq = tid & 7;    // 0..7  col-chunk (8 cols)

  const float* r0 = W + (size_t)(k0 + 2 * a) * N + n0 + bq * 8;
  const float* r1 = r0 + N;
  float4 v00 = *(const float4*)r0;
  float4 v01 = *(const float4*)(r0 + 4);
  float4 v10 = *(const float4*)r1;
  float4 v11 = *(const float4*)(r1 + 4);
  float e0[8] = {v00.x, v00.y, v00.z, v00.w, v01.x, v01.y, v01.z, v01.w};
  float e1[8] = {v10.x, v10.y, v10.z, v10.w, v11.x, v11.y, v11.z, v11.w};
#pragma unroll
  for (int j = 0; j < 8; j++) {
    unsigned int val = (unsigned int)f2bf_raw(e0[j]) | ((unsigned int)f2bf_raw(e1[j]) << 16);
    t32[(bq * 8 + j) * 33 + a] = val;
  }
  __syncthreads();
  const int nl = tid >> 2, part = tid & 3;
  unsigned int c[8];
#pragma unroll
  for (int i = 0; i < 8; i++) c[i] = t32[nl * 33 + part * 8 + i];
  char* dst = (char*)(WT + (size_t)(n0 + nl) * K + k0 + part * 16);
  uint4 lo; lo.x = c[0]; lo.y = c[1]; lo.z = c[2]; lo.w = c[3];
  uint4 hi; hi.x = c[4]; hi.y = c[5]; hi.z = c[6]; hi.w = c[7];
  *(uint4*)dst = lo;
  *(uint4*)(dst + 16) = hi;
}

// ---------------- v (b,t,h,dv) bf16 -> vS[bh][kt][chunk(4)][dv(512)] 16B units ----------------
__global__ void k_build_vS(const ushort_t* __restrict__ v, ushort_t* __restrict__ vS) {
  __shared__ ushort_t t[32 * 520];
  const int tid = threadIdx.x;
  const int kt = blockIdx.x;
  const int bh = blockIdx.y;
  const int b = bh >> 3, h = bh & 7;
#pragma unroll
  for (int r = 0; r < 8; r++) {
    int j = r * 4 + (tid >> 6);
    int vec = tid & 63;
    us8 d = *(const us8*)(v + (((size_t)(b * Tn + kt * 32 + j) * NH + h) * DVv) + vec * 8);
    *(us8*)(&t[j * 520 + vec * 8]) = d;
  }
  __syncthreads();
#pragma unroll
  for (int u = 0; u < 8; u++) {
    int uid = u * 256 + tid;
    int chunk = uid >> 9;
    int dv = uid & 511;
    us8 o;
#pragma unroll
    for (int jj = 0; jj < 8; jj++) o[jj] = t[(chunk * 8 + jj) * 520 + dv];
    *(us8*)(vS + ((size_t)(bh * 64 + kt) * 2048 + chunk * 512 + dv) * 8) = o;
  }
}

// ---------------- RoPE in-place on bf16 (b,t,h,dk), scale folded ----------------
__global__ void k_rope(bf16* __restrict__ x, float scale) {
  int tid = blockIdx.x * 256 + threadIdx.x;
  int i = tid & 127;
  int h = (tid >> 7) & 7;
  int t = (tid >> 10) & (Tn - 1);
  int b = tid >> 21;
  float inv = exp2f(-(float)i * (13.287712379549449f / 128.0f));
  float ang = (float)t * inv;
  float s, c;
  sincosf(ang, &s, &c);
  size_t base = ((size_t)(b * Tn + t) * NH + h) * DKk + i;
  float x1 = __bfloat162float(x[base]);
  float x2 = __bfloat162float(x[base + 128]);
  x[base]       = __float2bfloat16((x1 * c - x2 * s) * scale);
  x[base + 128] = __float2bfloat16((x2 * c + x1 * s) * scale);
}

// ================= 256x256 8-phase GEMM, v3 (R5/R7-measured best: 45.6% MfmaUtil) ==========
// Per phase: {ds-read subtile ∥ stage 1 half-tile ∥ 16 MFMA}; quadrants Q00,Q10,Q01,Q11;
// stages B(t+1)@ph1/2, A(t+2)@ph3/4, B(t+2)@ph5/6, A(t+3)@ph7/8; vmcnt(4) at ph4/ph8 only.
// MEASURED LOCAL OPTIMUM — R6 counted-lgkm read-ahead: −9%; R8 deep-slack stages: −5%.
// Do not perturb the phase schedule without a within-probe A/B.
// Split-K via blockIdx.z (F32S=true -> fp32 partials O0/O1 for k_add2_f32 reduce).
#define BARX() asm volatile("s_barrier" ::: "memory")
#define LGKM0() { asm volatile("s_waitcnt lgkmcnt(0)" ::: "memory"); __builtin_amdgcn_sched_barrier(0); }
#define VMW4() asm volatile("s_waitcnt vmcnt(4)" ::: "memory")
#define VMW0() asm volatile("s_waitcnt vmcnt(0)" ::: "memory")
#define PRIO1 __builtin_amdgcn_s_setprio(1)
#define PRIO0 __builtin_amdgcn_s_setprio(0)

#define QUADQ(MB, NB)                                                              \
  { _Pragma("unroll") for (int kk_ = 0; kk_ < 2; ++kk_)                            \
    _Pragma("unroll") for (int mf_ = 0; mf_ < 4; ++mf_)                            \
    _Pragma("unroll") for (int nf_ = 0; nf_ < 2; ++nf_)                            \
      acc[(MB) + mf_][(NB) + nf_] = __builtin_amdgcn_mfma_f32_16x16x32_bf16(       \
          ar[(MB) + mf_][kk_], br[(NB) + nf_][kk_],                                \
          acc[(MB) + mf_][(NB) + nf_], 0, 0, 0); }

template <bool F32S>
__global__ __launch_bounds__(512, 2) void k_gemm8(const bf16* __restrict__ A, const bf16* __restrict__ BT,
                                                  void* __restrict__ O0, void* __restrict__ O1,
                                                  int nsplit, int M, int Ntot, int Kloop, int Kstride) {
  extern __shared__ char lds[];
  const int tid = threadIdx.x;
  const int lane = tid & 63;
  const int w = tid >> 6;        // 0..7
  const int wr = w >> 2;         // 0..1 (M half)
  const int wc = w & 3;          // 0..3 (N quarter)
  const int quad = lane >> 4, c16 = lane & 15;
  const int m0 = blockIdx.y * 256, n0 = blockIdx.x * 256;
  const int ks = blockIdx.z;

  const bf16* Ab = A + (size_t)ks * Kloop;
  const bf16* Bb = BT + (size_t)ks * Kloop;

  const int srow = (w << 4) | (lane >> 3);
  const int gsw = (((lane & 7) ^ (lane >> 3)) << 4);   // inverse-swizzled source granule
  const size_t rowBytes = (size_t)Kstride * 2;
  const char* aS = (const char*)(Ab + (size_t)(m0 + srow) * Kstride) + gsw;
  const char* bS = (const char*)(Bb + (size_t)(n0 + srow) * Kstride) + gsw;

  auto stage = [&](int matB, int buf, int h, int t) {
    const char* base = (matB ? bS : aS) + (size_t)h * 128 * rowBytes + (size_t)t * 128;
    char* ldst = lds + buf * 65536 + matB * 32768 + h * 16384 + w * 2048;
    gload_lds16(base, ldst);
    gload_lds16(base + 8 * rowBytes, ldst + 1024);
  };
  auto ldA = [&](int buf, int mf, int kk) -> bf16x8 {
    int row = wr * 128 + mf * 16 + c16;
    return *(const bf16x8*)(lds + buf * 65536 + row * 128 + ((((kk << 2) | quad) ^ (c16 & 7)) << 4));
  };
  auto ldB = [&](int buf, int nf, int kk) -> bf16x8 {
    int row = wc * 64 + nf * 16 + c16;
    return *(const bf16x8*)(lds + buf * 65536 + 32768 + row * 128 + ((((kk << 2) | quad) ^ (c16 & 7)) << 4));
  };

  f32x4 acc[8][4];
  const f32x4 fz = {0.f, 0.f, 0.f, 0.f};
#pragma unroll
  for (int i = 0; i < 8; i++)
#pragma unroll
    for (int j = 0; j < 4; j++) acc[i][j] = fz;
  bf16x8 ar[8][2], br[4][2];

  const int nT = Kloop >> 6;
  const int nIter = nT >> 1;

  // prologue: tile0 full + tile1 A -> 12 loads; vmcnt(4) leaves t1.A in flight
  stage(0, 0, 0, 0); stage(0, 0, 1, 0);
  stage(1, 0, 0, 0); stage(1, 0, 1, 0);
  stage(0, 1, 0, 1); stage(0, 1, 1, 1);
  VMW4();
  BARX();

  for (int it = 0; it < nIter; ++it) {
    const int t = it * 2;
    const bool last = (it == nIter - 1);
    // ---- ph1: ds A0-3 + B01 (buf0); stage (t+1)B0; Q00 ----
#pragma unroll
    for (int mf = 0; mf < 4; ++mf) { ar[mf][0] = ldA(0, mf, 0); ar[mf][1] = ldA(0, mf, 1); }
#pragma unroll
    for (int nf = 0; nf < 2; ++nf) { br[nf][0] = ldB(0, nf, 0); br[nf][1] = ldB(0, nf, 1); }
    stage(1, 1, 0, t + 1);
    BARX(); LGKM0();
    PRIO1; QUADQ(0, 0); PRIO0;
    BARX();
    // ---- ph2: ds A4-7 (buf0); stage (t+1)B1; Q10 ----
#pragma unroll
    for (int mf = 4; mf < 8; ++mf) { ar[mf][0] = ldA(0, mf, 0); ar[mf][1] = ldA(0, mf, 1); }
    stage(1, 1, 1, t + 1);
    BARX(); LGKM0();
    PRIO1; QUADQ(4, 0); PRIO0;
    BARX();
    // ---- ph3: ds B23 (buf0); stage (t+2)A0; Q01 ----
#pragma unroll
    for (int nf = 2; nf < 4; ++nf) { br[nf][0] = ldB(0, nf, 0); br[nf][1] = ldB(0, nf, 1); }
    if (!last) stage(0, 0, 0, t + 2);
    BARX(); LGKM0();
    PRIO1; QUADQ(0, 2); PRIO0;
    BARX();
    // ---- ph4: stage (t+2)A1; Q11; vmcnt(4) -> tile t+1 landed ----
    if (!last) stage(0, 0, 1, t + 2);
    BARX();
    PRIO1; QUADQ(4, 2); PRIO0;
    if (!last) { VMW4(); } else { VMW0(); }
    BARX();
    // ---- ph5: ds A0-3 + B01 (buf1); stage (t+2)B0; Q00 ----
#pragma unroll
    for (int mf = 0; mf < 4; ++mf) { ar[mf][0] = ldA(1, mf, 0); ar[mf][1] = ldA(1, mf, 1); }
#pragma unroll
    for (int nf = 0; nf < 2; ++nf) { br[nf][0] = ldB(1, nf, 0); br[nf][1] = ldB(1, nf, 1); }
    if (!last) stage(1, 0, 0, t + 2);
    BARX(); LGKM0();
    PRIO1; QUADQ(0, 0); PRIO0;
    BARX();
    // ---- ph6: ds A4-7 (buf1); stage (t+2)B1; Q10 ----
#pragma unroll
    for (int mf = 4; mf < 8; ++mf) { ar[mf][0] = ldA(1, mf, 0); ar[mf][1] = ldA(1, mf, 1); }
    if (!last) stage(1, 0, 1, t + 2);
    BARX(); LGKM0();
    PRIO1; QUADQ(4, 0); PRIO0;
    BARX();
    // ---- ph7: ds B23 (buf1); stage (t+3)A0; Q01 ----
#pragma unroll
    for (int nf = 2; nf < 4; ++nf) { br[nf][0] = ldB(1, nf, 0); br[nf][1] = ldB(1, nf, 1); }
    if (!last) stage(0, 1, 0, t + 3);
    BARX(); LGKM0();
    PRIO1; QUADQ(0, 2); PRIO0;
    BARX();
    // ---- ph8: stage (t+3)A1; Q11; vmcnt(4) ----
    if (!last) stage(0, 1, 1, t + 3);
    BARX();
    PRIO1; QUADQ(4, 2); PRIO0;
    if (!last) VMW4();
    BARX();
  }

  if (F32S) {
    // split-K fp32 partial: z selects buffer, full N width
    float* Ob = (float*)(ks ? O1 : O0);
#pragma unroll
    for (int mf = 0; mf < 8; ++mf)
#pragma unroll
      for (int nf = 0; nf < 4; ++nf)
#pragma unroll
        for (int rr = 0; rr < 4; ++rr) {
          int m = m0 + wr * 128 + mf * 16 + quad * 4 + rr;
          int n = n0 + wc * 64 + nf * 16 + c16;
          Ob[(size_t)m * Ntot + n] = acc[mf][nf][rr];
        }
  } else {
    // dual bf16 outputs split at n = nsplit
    bf16* Ob; int ldo, nc0;
    if (n0 < nsplit) { Ob = (bf16*)O0; ldo = nsplit; nc0 = n0; }
    else             { Ob = (bf16*)O1; ldo = Ntot - nsplit; nc0 = n0 - nsplit; }
#pragma unroll
    for (int mf = 0; mf < 8; ++mf)
#pragma unroll
      for (int nf = 0; nf < 4; ++nf)
#pragma unroll
        for (int rr = 0; rr < 4; ++rr) {
          int m = m0 + wr * 128 + mf * 16 + quad * 4 + rr;
          int n = nc0 + wc * 64 + nf * 16 + c16;
          Ob[(size_t)m * ldo + n] = __float2bfloat16(acc[mf][nf][rr]);
        }
  }
}

// ---------------- Retention v4 (R5/R7-measured best): rotated loop {PV(t-1); S(t)} ----------------
// K-dbuf + V-sbuf + P-dbuf, LDS 76.8KB -> 2 blocks/CU + counted-vmcnt pipelining.
// Ledger verified in R4/R5. (v5 swapped-S + shfl redistribute regressed in R6 — do not reapply.)
__global__ __launch_bounds__(256, 2) void k_retention(const bf16* __restrict__ q, const bf16* __restrict__ k,
                                                      const char* __restrict__ vS, const bf16* __restrict__ g,
                                                      const float* __restrict__ gnw, bf16* __restrict__ X) {
  extern __shared__ char smem[];
  ushort_t* p_lds_base = (ushort_t*)(smem + 65536);
  float* red = (float*)(smem + 75776);
  bf16* o_lds = (bf16*)smem;   // epilogue alias (64KB)

  const int tid = threadIdx.x;
  const int l = tid & 63, w = tid >> 6;
  const int quad = l >> 4, c16 = l & 15;

  const int bid = blockIdx.x;
  const int u = (bid & 255) >> 4;
  const int qt = (bid < 256) ? (31 - u) : u;   // heavy half then light half
  const int bh = bid & 15;
  const int b = bh >> 3, h = bh & 7;
  const int q0 = qt * 64;

  bf16x8 qf[8];
  {
    const bf16* qrow = q + ((size_t)(b * Tn + q0 + w * 16 + c16) * NH + h) * DKk + quad * 8;
#pragma unroll
    for (int c = 0; c < 8; c++) qf[c] = *(const bf16x8*)(qrow + c * 32);
  }

  const float log2g = log2f(1.0f - exp2f(-5.0f - (float)h));

  f32x4 acc[4][8];
  const f32x4 fz = {0.f, 0.f, 0.f, 0.f};
#pragma unroll
  for (int rt = 0; rt < 4; rt++)
#pragma unroll
    for (int n = 0; n < 8; n++) acc[rt][n] = fz;

  const int ktmax = 2 * qt + 1;
  const float Dcut = 30.0f / (-log2g);
  int kt0 = (int)fmaxf(0.0f, floorf(((float)q0 - Dcut) * (1.0f / 32.0f)));

  const char* vS_tilebase = vS + (size_t)(bh * 64) * 32768;

  auto stageK = [&](int kt) {
    const int pb = (kt - kt0) & 1;
#pragma unroll
    for (int i = 0; i < 4; i++) {
      int instr = w * 4 + i;
      int j = instr * 2 + (l >> 5);
      int cg = (l & 31) ^ (j & 7);
      const char* gp = (const char*)(k + ((size_t)(b * Tn + kt * 32 + j) * NH + h) * DKk) + cg * 16;
      gload_lds16(gp, smem + pb * 16384 + instr * 1024);
    }
  };
  auto stageV = [&](int kt) {
#pragma unroll
    for (int i = 0; i < 8; i++) {
      int instr = w * 8 + i;
      const char* gp = vS_tilebase + (size_t)kt * 32768 + instr * 1024 + l * 16;
      gload_lds16(gp, smem + 32768 + instr * 1024);
    }
  };

  auto S_phase = [&](int kt) {
    const int pb = (kt - kt0) & 1;
    f32x4 sacc[2] = {fz, fz};
#pragma unroll
    for (int jt = 0; jt < 2; jt++)
#pragma unroll
      for (int c = 0; c < 8; c++) {
        const char* kp = smem + pb * 16384 + (jt * 16 + c16) * 512 + (((c * 4 + quad) ^ (c16 & 7)) * 16);
        bf16x8 bfrag = *(const bf16x8*)kp;
        sacc[jt] = __builtin_amdgcn_mfma_f32_16x16x32_bf16(qf[c], bfrag, sacc[jt], 0, 0, 0);
      }
    ushort_t* pbuf = p_lds_base + pb * 2560;
#pragma unroll
    for (int jt = 0; jt < 2; jt++)
#pragma unroll
      for (int r = 0; r < 4; r++) {
        int ig = q0 + w * 16 + quad * 4 + r;
        int jg = kt * 32 + jt * 16 + c16;
        int d = ig - jg;
        float val = (d >= 0) ? sacc[jt][r] * exp2f(log2g * (float)d) : 0.0f;
        pbuf[(w * 16 + quad * 4 + r) * 40 + jt * 16 + c16] = f2bf_raw(val);
      }
  };

  auto PV_phase = [&](int kt) {
    const int pb = (kt - kt0) & 1;
    const char* pbuf = (const char*)(p_lds_base + pb * 2560);
    bf16x8 pa[4];
#pragma unroll
    for (int rt = 0; rt < 4; rt++)
      pa[rt] = *(const bf16x8*)(pbuf + (rt * 16 + c16) * 80 + quad * 16);
    const char* v_lds = smem + 32768;
#pragma unroll
    for (int n = 0; n < 8; n++) {
      bf16x8 bv = *(const bf16x8*)(v_lds + quad * 8192 + (w * 128 + n * 16 + c16) * 16);
#pragma unroll
      for (int rt = 0; rt < 4; rt++)
        acc[rt][n] = __builtin_amdgcn_mfma_f32_16x16x32_bf16(pa[rt], bv, acc[rt][n], 0, 0, 0);
    }
  };

#define SBARR() { __builtin_amdgcn_sched_barrier(0); __builtin_amdgcn_s_barrier(); }
#define WLGKM0() { asm volatile("s_waitcnt lgkmcnt(0)" ::: "memory"); }

  // ---- peeled first iteration (S-only) ----
  stageK(kt0);                                        // out: K(kt0)(4)  [+qf(8) older]
  stageV(kt0);                                        // out: +V(kt0)(8)
  asm volatile("s_waitcnt vmcnt(8)" ::: "memory");    // drains qf + K(kt0); V(kt0) flies
  SBARR();
  S_phase(kt0);
  if (kt0 + 1 <= ktmax) stageK(kt0 + 1);              // out: V(kt0)(8), K(kt0+1)(4)
  WLGKM0(); SBARR();

  // ---- main loop ----
  for (int kt = kt0 + 1; kt <= ktmax; ++kt) {
    asm volatile("s_waitcnt vmcnt(4)" ::: "memory");  // V(kt-1) landed; K(kt) flies
    SBARR();
    PV_phase(kt - 1);
    WLGKM0(); SBARR();                                // V buf + p[kt-1] free
    stageV(kt);                                       // out: K(kt)(4), V(kt)(8)
    asm volatile("s_waitcnt vmcnt(8)" ::: "memory");  // K(kt) landed; V(kt) flies
    SBARR();
    S_phase(kt);
    if (kt + 1 <= ktmax) stageK(kt + 1);              // out: V(kt)(8), K(kt+1)(4)
    WLGKM0(); SBARR();                                // p[kt] visible
  }

  // ---- epilogue PV(ktmax) ----
  asm volatile("s_waitcnt vmcnt(0)" ::: "memory");
  SBARR();
  PV_phase(ktmax);

  // RMS: wave has 128-dv partial for all 64 rows -> cross-wave combine via red
  __syncthreads();
#pragma unroll
  for (int rt = 0; rt < 4; rt++)
#pragma unroll
    for (int r = 0; r < 4; r++) {
      float s = 0.f;
#pragma unroll
      for (int n = 0; n < 8; n++) { float v = acc[rt][n][r]; s += v * v; }
      s += __shfl_xor(s, 1);
      s += __shfl_xor(s, 2);
      s += __shfl_xor(s, 4);
      s += __shfl_xor(s, 8);
      if (c16 == 0) red[(rt * 16 + quad * 4 + r) * 4 + w] = s;
    }
  __syncthreads();
  float ss[4][4];
#pragma unroll
  for (int rt = 0; rt < 4; rt++)
#pragma unroll
    for (int r = 0; r < 4; r++) {
      int row = rt * 16 + quad * 4 + r;
      float tot = red[row * 4] + red[row * 4 + 1] + red[row * 4 + 2] + red[row * 4 + 3];
      ss[rt][r] = rsqrtf(tot * (1.0f / DVv) + EPSf);
    }
  __syncthreads();

#pragma unroll
  for (int n = 0; n < 8; n++) {
    int col = w * 128 + n * 16 + c16;
    float gw = gnw[col];
#pragma unroll
    for (int rt = 0; rt < 4; rt++)
#pragma unroll
      for (int r = 0; r < 4; r++) {
        int row = rt * 16 + quad * 4 + r;
        o_lds[row * 512 + col] = __float2bfloat16(acc[rt][n][r] * ss[rt][r] * gw);
      }
  }
  __syncthreads();

#pragma unroll
  for (int it = 0; it < 16; it++) {
    int cid = it * 256 + tid;
    int row = cid >> 6;
    int cp = (cid & 63) * 8;
    const ushort_t* gp = (const ushort_t*)g + ((size_t)(b * Tn + q0 + row) * NH + h) * DVv + cp;
    us8 gv = *(const us8*)gp;
    us8 ov;
#pragma unroll
    for (int e = 0; e < 8; e++) {
      float gf = bf2f_raw(gv[e]);
      float gate = gf / (1.0f + expf(-gf));
      float of = __bfloat162float(o_lds[row * 512 + cp + e]);
      ov[e] = f2bf_raw(of * gate);
    }
    *(us8*)((ushort_t*)X + ((size_t)(b * Tn + q0 + row) * NH + h) * DVv + cp) = ov;
  }
}

extern "C" void kernel_launch(void* const* d_in, const int* in_sizes, int n_in,
                              void* d_out, int out_size, void* d_ws, size_t ws_size,
                              hipStream_t stream) {
  const float* hs  = (const float*)d_in[0];
  const float* Wq  = (const float*)d_in[1];
  const float* Wk  = (const float*)d_in[2];
  const float* Wv  = (const float*)d_in[3];
  const float* Wg  = (const float*)d_in[4];
  const float* Wo  = (const float*)d_in[5];
  const float* gnw = (const float*)d_in[6];
  float* out = (float*)d_out;
  char* ws = (char*)d_ws;

  bf16* hsb = (bf16*)(ws);                    // 16 MB
  bf16* WqT = (bf16*)(ws + 16777216);         //  8 MB  } contiguous [4096][2048] for fused qk
  bf16* WkT = (bf16*)(ws + 25165824);         //  8 MB  }
  bf16* WvT = (bf16*)(ws + 33554432);         // 16 MB  } contiguous [8192][2048] for fused vg
  bf16* WgT = (bf16*)(ws + 50331648);         // 16 MB  }
  char* vSb = ws;                              // alias hsb/WqT/WkT (dead after q/k/v/g GEMMs)
  bf16* WoT = (bf16*)(ws + 33554432);         // alias WvT (dead after vg GEMM)
  bf16* qb = (bf16*)(ws + 67108864);          // 16 MB
  bf16* kb = (bf16*)(ws + 83886080);          // 16 MB
  bf16* vb = (bf16*)(ws + 100663296);         // 32 MB
  bf16* gb = (bf16*)(ws + 134217728);         // 32 MB
  bf16* Xb = vb;                               // alias v (dead after vS build)
  float* p0 = (float*)ws;                      // 32 MB fp32 partial (alias vSb, dead after retention)
  float* p1 = (float*)(ws + 50331648);         // 32 MB fp32 partial (alias WgT+qb, dead after retention)

  static bool attr_done = false;
  if (!attr_done) {
    hipFuncSetAttribute((const void*)k_gemm8<false>, hipFuncAttributeMaxDynamicSharedMemorySize, 131072);
    hipFuncSetAttribute((const void*)k_gemm8<true>, hipFuncAttributeMaxDynamicSharedMemorySize, 131072);
    hipFuncSetAttribute((const void*)k_retention, hipFuncAttributeMaxDynamicSharedMemorySize, 76800);
    attr_done = true;
  }

  k_f32_to_bf16<<<8192, 256, 0, stream>>>((const float4*)hs, (ushort4*)hsb, 2097152);
  k_transpose64<<<dim3(HID / 64, HID / 64), 256, 0, stream>>>(Wq, WqT, HID, HID);
  k_transpose64<<<dim3(HID / 64, HID / 64), 256, 0, stream>>>(Wk, WkT, HID, HID);
  k_transpose64<<<dim3(NH * DVv / 64, HID / 64), 256, 0, stream>>>(Wv, WvT, HID, NH * DVv);
  k_transpose64<<<dim3(NH * DVv / 64, HID / 64), 256, 0, stream>>>(Wg, WgT, HID, NH * DVv);
  // fused q|k: C[4096][4096] = hsb @ [WqT|WkT]^T, split at n=2048 -> qb, kb
  k_gemm8<false><<<dim3(16, 16), 512, 131072, stream>>>(hsb, WqT, qb, kb, 2048, 4096, 4096, 2048, 2048);
  // fused v|g: C[4096][8192] = hsb @ [WvT|WgT]^T, split at n=4096 -> vb, gb
  k_gemm8<false><<<dim3(32, 16), 512, 131072, stream>>>(hsb, WvT, vb, gb, 4096, 4096, 8192, 2048, 2048);
  k_rope<<<16384, 256, 0, stream>>>(qb, 0.0625f);
  k_rope<<<16384, 256, 0, stream>>>(kb, 1.0f);
  k_build_vS<<<dim3(64, 16), 256, 0, stream>>>((const ushort_t*)vb, (ushort_t*)vSb);
  k_transpose64<<<dim3(HID / 64, NH * DVv / 64), 256, 0, stream>>>(Wo, WoT, NH * DVv, HID);
  k_retention<<<512, 256, 76800, stream>>>(qb, kb, vSb, gb, gnw, Xb);
  // out-proj split-K=2 through the 8-phase kernel: 256 blocks (full GPU), fp32 partials + reduce
  k_gemm8<true><<<dim3(8, 16, 2), 512, 131072, stream>>>(Xb, WoT, p0, p1, 2048, 4096, 2048, 2048, 4096);
  k_add2_f32<<<8192, 256, 0, stream>>>((const float4*)p0, (const float4*)p1, (float4*)out, 2097152);
}

// Round 10
// 588.213 us; speedup vs baseline: 1.0340x; 1.0301x over previous
//
#include <hip/hip_runtime.h>
#include <hip/hip_bf16.h>
#include <math.h>

#define NH 8
#define DKk 256
#define DVv 512
#define Bn 2
#define Tn 2048
#define HID 2048
#define EPSf 1e-5f

typedef __bf16 bf16x8 __attribute__((ext_vector_type(8)));
typedef float f32x4 __attribute__((ext_vector_type(4)));
typedef unsigned short us8 __attribute__((ext_vector_type(8)));
using bf16 = __hip_bfloat16;
typedef unsigned short ushort_t;

__device__ __forceinline__ void gload_lds16(const void* g, void* lds_base) {
  __builtin_amdgcn_global_load_lds(
      (const __attribute__((address_space(1))) void*)g,
      (__attribute__((address_space(3))) void*)lds_base, 16, 0, 0);
}

__device__ __forceinline__ ushort_t f2bf_raw(float f) {
  bf16 h = __float2bfloat16(f);
  return *reinterpret_cast<ushort_t*>(&h);
}
__device__ __forceinline__ float bf2f_raw(ushort_t u) {
  union { unsigned int i; float f; } v; v.i = ((unsigned int)u) << 16; return v.f;
}

// ---------------- fp32 -> bf16 elementwise (vectorized x4) ----------------
__global__ void k_f32_to_bf16(const float4* __restrict__ in, ushort4* __restrict__ out, int n4) {
  int i = blockIdx.x * blockDim.x + threadIdx.x;
  if (i >= n4) return;
  float4 v = in[i];
  ushort4 o;
  o.x = f2bf_raw(v.x); o.y = f2bf_raw(v.y); o.z = f2bf_raw(v.z); o.w = f2bf_raw(v.w);
  out[i] = o;
}

// ---------------- fp32 a + b -> out (vectorized x4), split-K reduce ----------------
__global__ void k_add2_f32(const float4* __restrict__ a, const float4* __restrict__ b,
                           float4* __restrict__ o, int n4) {
  int i = blockIdx.x * blockDim.x + threadIdx.x;
  if (i >= n4) return;
  float4 x = a[i], y = b[i];
  float4 r; r.x = x.x + y.x; r.y = x.y + y.y; r.z = x.z + y.z; r.w = x.w + y.w;
  o[i] = r;
}

// ---------------- W (K,N) fp32 -> WT (N,K) bf16, 64x64 tile (R9: neutral vs 32x32; keep) ----
__global__ __launch_bounds__(256) void k_transpose64(const float* __restrict__ W, bf16* __restrict__ WT,
                                                     int K, int N) {
  __shared__ unsigned int t32[64 * 33];  // 8448 B
  const int tid = threadIdx.x;
  const int n0 = blockIdx.x * 64, k0 = blockIdx.y * 64;
  const int a = tid >> 3;    // 0..31 row-pair
  const int bq = tid & 7;    // 0..7  col-chunk (8 cols)

  const float* r0 = W + (size_t)(k0 + 2 * a) * N + n0 + bq * 8;
  const float* r1 = r0 + N;
  float4 v00 = *(const float4*)r0;
  float4 v01 = *(const float4*)(r0 + 4);
  float4 v10 = *(const float4*)r1;
  float4 v11 = *(const float4*)(r1 + 4);
  float e0[8] = {v00.x, v00.y, v00.z, v00.w, v01.x, v01.y, v01.z, v01.w};
  float e1[8] = {v10.x, v10.y, v10.z, v10.w, v11.x, v11.y, v11.z, v11.w};
#pragma unroll
  for (int j = 0; j < 8; j++) {
    unsigned int val = (unsigned int)f2bf_raw(e0[j]) | ((unsigned int)f2bf_raw(e1[j]) << 16);
    t32[(bq * 8 + j) * 33 + a] = val;
  }
  __syncthreads();
  const int nl = tid >> 2, part = tid & 3;
  unsigned int c[8];
#pragma unroll
  for (int i = 0; i < 8; i++) c[i] = t32[nl * 33 + part * 8 + i];
  char* dst = (char*)(WT + (size_t)(n0 + nl) * K + k0 + part * 16);
  uint4 lo; lo.x = c[0]; lo.y = c[1]; lo.z = c[2]; lo.w = c[3];
  uint4 hi; hi.x = c[4]; hi.y = c[5]; hi.z = c[6]; hi.w = c[7];
  *(uint4*)dst = lo;
  *(uint4*)(dst + 16) = hi;
}

// ---------------- v (b,t,h,dv) bf16 -> vS[bh][kt][chunk(4)][dv(512)] 16B units ----------------
__global__ void k_build_vS(const ushort_t* __restrict__ v, ushort_t* __restrict__ vS) {
  __shared__ ushort_t t[32 * 520];
  const int tid = threadIdx.x;
  const int kt = blockIdx.x;
  const int bh = blockIdx.y;
  const int b = bh >> 3, h = bh & 7;
#pragma unroll
  for (int r = 0; r < 8; r++) {
    int j = r * 4 + (tid >> 6);
    int vec = tid & 63;
    us8 d = *(const us8*)(v + (((size_t)(b * Tn + kt * 32 + j) * NH + h) * DVv) + vec * 8);
    *(us8*)(&t[j * 520 + vec * 8]) = d;
  }
  __syncthreads();
#pragma unroll
  for (int u = 0; u < 8; u++) {
    int uid = u * 256 + tid;
    int chunk = uid >> 9;
    int dv = uid & 511;
    us8 o;
#pragma unroll
    for (int jj = 0; jj < 8; jj++) o[jj] = t[(chunk * 8 + jj) * 520 + dv];
    *(us8*)(vS + ((size_t)(bh * 64 + kt) * 2048 + chunk * 512 + dv) * 8) = o;
  }
}

// ================= 256x256 8-phase GEMM, v3 (R5/R7-measured best: 45.6% MfmaUtil) ==========
// Per phase: {ds-read subtile ∥ stage 1 half-tile ∥ 16 MFMA}; quadrants Q00,Q10,Q01,Q11;
// stages B(t+1)@ph1/2, A(t+2)@ph3/4, B(t+2)@ph5/6, A(t+3)@ph7/8; vmcnt(4) at ph4/ph8 only.
// MEASURED LOCAL OPTIMUM — R6 counted-lgkm read-ahead: −9%; R8 deep-slack stages: −5%.
// Do not perturb the phase schedule without a within-probe A/B.
// F32S=true: split-K via blockIdx.z -> fp32 partials O0/O1 (k_add2_f32 reduce).
// ROPE=true: fused RoPE epilogue (qk GEMM) — stage tile to LDS, rotate pairs (i, i+128),
// scale folded (q: 0.0625, k: 1.0), write q/k directly. Saves 2 rope launches + 64MB traffic.
#define BARX() asm volatile("s_barrier" ::: "memory")
#define LGKM0() { asm volatile("s_waitcnt lgkmcnt(0)" ::: "memory"); __builtin_amdgcn_sched_barrier(0); }
#define VMW4() asm volatile("s_waitcnt vmcnt(4)" ::: "memory")
#define VMW0() asm volatile("s_waitcnt vmcnt(0)" ::: "memory")
#define PRIO1 __builtin_amdgcn_s_setprio(1)
#define PRIO0 __builtin_amdgcn_s_setprio(0)

#define QUADQ(MB, NB)                                                              \
  { _Pragma("unroll") for (int kk_ = 0; kk_ < 2; ++kk_)                            \
    _Pragma("unroll") for (int mf_ = 0; mf_ < 4; ++mf_)                            \
    _Pragma("unroll") for (int nf_ = 0; nf_ < 2; ++nf_)                            \
      acc[(MB) + mf_][(NB) + nf_] = __builtin_amdgcn_mfma_f32_16x16x32_bf16(       \
          ar[(MB) + mf_][kk_], br[(NB) + nf_][kk_],                                \
          acc[(MB) + mf_][(NB) + nf_], 0, 0, 0); }

template <bool F32S, bool ROPE>
__global__ __launch_bounds__(512, 2) void k_gemm8(const bf16* __restrict__ A, const bf16* __restrict__ BT,
                                                  void* __restrict__ O0, void* __restrict__ O1,
                                                  int nsplit, int M, int Ntot, int Kloop, int Kstride) {
  extern __shared__ char lds[];
  const int tid = threadIdx.x;
  const int lane = tid & 63;
  const int w = tid >> 6;        // 0..7
  const int wr = w >> 2;         // 0..1 (M half)
  const int wc = w & 3;          // 0..3 (N quarter)
  const int quad = lane >> 4, c16 = lane & 15;
  const int m0 = blockIdx.y * 256, n0 = blockIdx.x * 256;
  const int ks = blockIdx.z;

  const bf16* Ab = A + (size_t)ks * Kloop;
  const bf16* Bb = BT + (size_t)ks * Kloop;

  const int srow = (w << 4) | (lane >> 3);
  const int gsw = (((lane & 7) ^ (lane >> 3)) << 4);   // inverse-swizzled source granule
  const size_t rowBytes = (size_t)Kstride * 2;
  const char* aS = (const char*)(Ab + (size_t)(m0 + srow) * Kstride) + gsw;
  const char* bS = (const char*)(Bb + (size_t)(n0 + srow) * Kstride) + gsw;

  auto stage = [&](int matB, int buf, int h, int t) {
    const char* base = (matB ? bS : aS) + (size_t)h * 128 * rowBytes + (size_t)t * 128;
    char* ldst = lds + buf * 65536 + matB * 32768 + h * 16384 + w * 2048;
    gload_lds16(base, ldst);
    gload_lds16(base + 8 * rowBytes, ldst + 1024);
  };
  auto ldA = [&](int buf, int mf, int kk) -> bf16x8 {
    int row = wr * 128 + mf * 16 + c16;
    return *(const bf16x8*)(lds + buf * 65536 + row * 128 + ((((kk << 2) | quad) ^ (c16 & 7)) << 4));
  };
  auto ldB = [&](int buf, int nf, int kk) -> bf16x8 {
    int row = wc * 64 + nf * 16 + c16;
    return *(const bf16x8*)(lds + buf * 65536 + 32768 + row * 128 + ((((kk << 2) | quad) ^ (c16 & 7)) << 4));
  };

  f32x4 acc[8][4];
  const f32x4 fz = {0.f, 0.f, 0.f, 0.f};
#pragma unroll
  for (int i = 0; i < 8; i++)
#pragma unroll
    for (int j = 0; j < 4; j++) acc[i][j] = fz;
  bf16x8 ar[8][2], br[4][2];

  const int nT = Kloop >> 6;
  const int nIter = nT >> 1;

  // prologue: tile0 full + tile1 A -> 12 loads; vmcnt(4) leaves t1.A in flight
  stage(0, 0, 0, 0); stage(0, 0, 1, 0);
  stage(1, 0, 0, 0); stage(1, 0, 1, 0);
  stage(0, 1, 0, 1); stage(0, 1, 1, 1);
  VMW4();
  BARX();

  for (int it = 0; it < nIter; ++it) {
    const int t = it * 2;
    const bool last = (it == nIter - 1);
    // ---- ph1: ds A0-3 + B01 (buf0); stage (t+1)B0; Q00 ----
#pragma unroll
    for (int mf = 0; mf < 4; ++mf) { ar[mf][0] = ldA(0, mf, 0); ar[mf][1] = ldA(0, mf, 1); }
#pragma unroll
    for (int nf = 0; nf < 2; ++nf) { br[nf][0] = ldB(0, nf, 0); br[nf][1] = ldB(0, nf, 1); }
    stage(1, 1, 0, t + 1);
    BARX(); LGKM0();
    PRIO1; QUADQ(0, 0); PRIO0;
    BARX();
    // ---- ph2: ds A4-7 (buf0); stage (t+1)B1; Q10 ----
#pragma unroll
    for (int mf = 4; mf < 8; ++mf) { ar[mf][0] = ldA(0, mf, 0); ar[mf][1] = ldA(0, mf, 1); }
    stage(1, 1, 1, t + 1);
    BARX(); LGKM0();
    PRIO1; QUADQ(4, 0); PRIO0;
    BARX();
    // ---- ph3: ds B23 (buf0); stage (t+2)A0; Q01 ----
#pragma unroll
    for (int nf = 2; nf < 4; ++nf) { br[nf][0] = ldB(0, nf, 0); br[nf][1] = ldB(0, nf, 1); }
    if (!last) stage(0, 0, 0, t + 2);
    BARX(); LGKM0();
    PRIO1; QUADQ(0, 2); PRIO0;
    BARX();
    // ---- ph4: stage (t+2)A1; Q11; vmcnt(4) -> tile t+1 landed ----
    if (!last) stage(0, 0, 1, t + 2);
    BARX();
    PRIO1; QUADQ(4, 2); PRIO0;
    if (!last) { VMW4(); } else { VMW0(); }
    BARX();
    // ---- ph5: ds A0-3 + B01 (buf1); stage (t+2)B0; Q00 ----
#pragma unroll
    for (int mf = 0; mf < 4; ++mf) { ar[mf][0] = ldA(1, mf, 0); ar[mf][1] = ldA(1, mf, 1); }
#pragma unroll
    for (int nf = 0; nf < 2; ++nf) { br[nf][0] = ldB(1, nf, 0); br[nf][1] = ldB(1, nf, 1); }
    if (!last) stage(1, 0, 0, t + 2);
    BARX(); LGKM0();
    PRIO1; QUADQ(0, 0); PRIO0;
    BARX();
    // ---- ph6: ds A4-7 (buf1); stage (t+2)B1; Q10 ----
#pragma unroll
    for (int mf = 4; mf < 8; ++mf) { ar[mf][0] = ldA(1, mf, 0); ar[mf][1] = ldA(1, mf, 1); }
    if (!last) stage(1, 0, 1, t + 2);
    BARX(); LGKM0();
    PRIO1; QUADQ(4, 0); PRIO0;
    BARX();
    // ---- ph7: ds B23 (buf1); stage (t+3)A0; Q01 ----
#pragma unroll
    for (int nf = 2; nf < 4; ++nf) { br[nf][0] = ldB(1, nf, 0); br[nf][1] = ldB(1, nf, 1); }
    if (!last) stage(0, 1, 0, t + 3);
    BARX(); LGKM0();
    PRIO1; QUADQ(0, 2); PRIO0;
    BARX();
    // ---- ph8: stage (t+3)A1; Q11; vmcnt(4) ----
    if (!last) stage(0, 1, 1, t + 3);
    BARX();
    PRIO1; QUADQ(4, 2); PRIO0;
    if (!last) VMW4();
    BARX();
  }

  if (ROPE) {
    // ---- fused RoPE epilogue: tile -> LDS [256 m][256 i] bf16 (128KB, exact fit) ----
    __syncthreads();   // all main-loop LDS reads complete before overwrite
    ushort_t* tile = (ushort_t*)lds;
#pragma unroll
    for (int mf = 0; mf < 8; ++mf)
#pragma unroll
      for (int nf = 0; nf < 4; ++nf)
#pragma unroll
        for (int rr = 0; rr < 4; ++rr) {
          int row = wr * 128 + mf * 16 + quad * 4 + rr;
          int col = wc * 64 + nf * 16 + c16;
          tile[row * 256 + col] = f2bf_raw(acc[mf][nf][rr]);
        }
    __syncthreads();
    const bool qside = (n0 < nsplit);
    bf16* Ob = (bf16*)(qside ? O0 : O1);
    const float scale = qside ? 0.0625f : 1.0f;
    const int h = (qside ? n0 : n0 - nsplit) >> 8;   // 256-col tile == exactly one head
    // unit u = j*512 + tid: row = u>>4, ch = u&15 -> 16 lanes read 256B contiguous (no conflict)
#pragma unroll
    for (int j = 0; j < 8; ++j) {
      int u = j * 512 + tid;
      int row = u >> 4;
      int ch = u & 15;
      const ushort_t* lp = tile + row * 256 + ch * 8;
      us8 lo = *(const us8*)lp;
      us8 hi = *(const us8*)(lp + 128);
      int m = m0 + row;                       // m = b*Tn + t
      float tf = (float)(m & (Tn - 1));       // t within sequence
      us8 olo, ohi;
#pragma unroll
      for (int e = 0; e < 8; ++e) {
        int i = ch * 8 + e;
        float inv = exp2f(-(float)i * (13.287712379549449f / 128.0f));
        float ang = tf * inv;
        float s, c;
        sincosf(ang, &s, &c);
        float x1 = bf2f_raw(lo[e]);
        float x2 = bf2f_raw(hi[e]);
        olo[e] = f2bf_raw((x1 * c - x2 * s) * scale);
        ohi[e] = f2bf_raw((x2 * c + x1 * s) * scale);
      }
      ushort_t* dst = (ushort_t*)Ob + ((size_t)m * NH + h) * DKk + ch * 8;
      *(us8*)dst = olo;
      *(us8*)(dst + 128) = ohi;
    }
  } else if (F32S) {
    // split-K fp32 partial: z selects buffer, full N width
    float* Ob = (float*)(ks ? O1 : O0);
#pragma unroll
    for (int mf = 0; mf < 8; ++mf)
#pragma unroll
      for (int nf = 0; nf < 4; ++nf)
#pragma unroll
        for (int rr = 0; rr < 4; ++rr) {
          int m = m0 + wr * 128 + mf * 16 + quad * 4 + rr;
          int n = n0 + wc * 64 + nf * 16 + c16;
          Ob[(size_t)m * Ntot + n] = acc[mf][nf][rr];
        }
  } else {
    // dual bf16 outputs split at n = nsplit
    bf16* Ob; int ldo, nc0;
    if (n0 < nsplit) { Ob = (bf16*)O0; ldo = nsplit; nc0 = n0; }
    else             { Ob = (bf16*)O1; ldo = Ntot - nsplit; nc0 = n0 - nsplit; }
#pragma unroll
    for (int mf = 0; mf < 8; ++mf)
#pragma unroll
      for (int nf = 0; nf < 4; ++nf)
#pragma unroll
        for (int rr = 0; rr < 4; ++rr) {
          int m = m0 + wr * 128 + mf * 16 + quad * 4 + rr;
          int n = nc0 + wc * 64 + nf * 16 + c16;
          Ob[(size_t)m * ldo + n] = __float2bfloat16(acc[mf][nf][rr]);
        }
  }
}

// ---------------- Retention v4 (R5/R7-measured best): rotated loop {PV(t-1); S(t)} ----------------
// K-dbuf + V-sbuf + P-dbuf, LDS 76.8KB -> 2 blocks/CU + counted-vmcnt pipelining.
// Ledger verified in R4/R5. (v5 swapped-S + shfl redistribute regressed in R6 — do not reapply.)
__global__ __launch_bounds__(256, 2) void k_retention(const bf16* __restrict__ q, const bf16* __restrict__ k,
                                                      const char* __restrict__ vS, const bf16* __restrict__ g,
                                                      const float* __restrict__ gnw, bf16* __restrict__ X) {
  extern __shared__ char smem[];
  ushort_t* p_lds_base = (ushort_t*)(smem + 65536);
  float* red = (float*)(smem + 75776);
  bf16* o_lds = (bf16*)smem;   // epilogue alias (64KB)

  const int tid = threadIdx.x;
  const int l = tid & 63, w = tid >> 6;
  const int quad = l >> 4, c16 = l & 15;

  const int bid = blockIdx.x;
  const int u = (bid & 255) >> 4;
  const int qt = (bid < 256) ? (31 - u) : u;   // heavy half then light half
  const int bh = bid & 15;
  const int b = bh >> 3, h = bh & 7;
  const int q0 = qt * 64;

  bf16x8 qf[8];
  {
    const bf16* qrow = q + ((size_t)(b * Tn + q0 + w * 16 + c16) * NH + h) * DKk + quad * 8;
#pragma unroll
    for (int c = 0; c < 8; c++) qf[c] = *(const bf16x8*)(qrow + c * 32);
  }

  const float log2g = log2f(1.0f - exp2f(-5.0f - (float)h));

  f32x4 acc[4][8];
  const f32x4 fz = {0.f, 0.f, 0.f, 0.f};
#pragma unroll
  for (int rt = 0; rt < 4; rt++)
#pragma unroll
    for (int n = 0; n < 8; n++) acc[rt][n] = fz;

  const int ktmax = 2 * qt + 1;
  const float Dcut = 30.0f / (-log2g);
  int kt0 = (int)fmaxf(0.0f, floorf(((float)q0 - Dcut) * (1.0f / 32.0f)));

  const char* vS_tilebase = vS + (size_t)(bh * 64) * 32768;

  auto stageK = [&](int kt) {
    const int pb = (kt - kt0) & 1;
#pragma unroll
    for (int i = 0; i < 4; i++) {
      int instr = w * 4 + i;
      int j = instr * 2 + (l >> 5);
      int cg = (l & 31) ^ (j & 7);
      const char* gp = (const char*)(k + ((size_t)(b * Tn + kt * 32 + j) * NH + h) * DKk) + cg * 16;
      gload_lds16(gp, smem + pb * 16384 + instr * 1024);
    }
  };
  auto stageV = [&](int kt) {
#pragma unroll
    for (int i = 0; i < 8; i++) {
      int instr = w * 8 + i;
      const char* gp = vS_tilebase + (size_t)kt * 32768 + instr * 1024 + l * 16;
      gload_lds16(gp, smem + 32768 + instr * 1024);
    }
  };

  auto S_phase = [&](int kt) {
    const int pb = (kt - kt0) & 1;
    f32x4 sacc[2] = {fz, fz};
#pragma unroll
    for (int jt = 0; jt < 2; jt++)
#pragma unroll
      for (int c = 0; c < 8; c++) {
        const char* kp = smem + pb * 16384 + (jt * 16 + c16) * 512 + (((c * 4 + quad) ^ (c16 & 7)) * 16);
        bf16x8 bfrag = *(const bf16x8*)kp;
        sacc[jt] = __builtin_amdgcn_mfma_f32_16x16x32_bf16(qf[c], bfrag, sacc[jt], 0, 0, 0);
      }
    ushort_t* pbuf = p_lds_base + pb * 2560;
#pragma unroll
    for (int jt = 0; jt < 2; jt++)
#pragma unroll
      for (int r = 0; r < 4; r++) {
        int ig = q0 + w * 16 + quad * 4 + r;
        int jg = kt * 32 + jt * 16 + c16;
        int d = ig - jg;
        float val = (d >= 0) ? sacc[jt][r] * exp2f(log2g * (float)d) : 0.0f;
        pbuf[(w * 16 + quad * 4 + r) * 40 + jt * 16 + c16] = f2bf_raw(val);
      }
  };

  auto PV_phase = [&](int kt) {
    const int pb = (kt - kt0) & 1;
    const char* pbuf = (const char*)(p_lds_base + pb * 2560);
    bf16x8 pa[4];
#pragma unroll
    for (int rt = 0; rt < 4; rt++)
      pa[rt] = *(const bf16x8*)(pbuf + (rt * 16 + c16) * 80 + quad * 16);
    const char* v_lds = smem + 32768;
#pragma unroll
    for (int n = 0; n < 8; n++) {
      bf16x8 bv = *(const bf16x8*)(v_lds + quad * 8192 + (w * 128 + n * 16 + c16) * 16);
#pragma unroll
      for (int rt = 0; rt < 4; rt++)
        acc[rt][n] = __builtin_amdgcn_mfma_f32_16x16x32_bf16(pa[rt], bv, acc[rt][n], 0, 0, 0);
    }
  };

#define SBARR() { __builtin_amdgcn_sched_barrier(0); __builtin_amdgcn_s_barrier(); }
#define WLGKM0() { asm volatile("s_waitcnt lgkmcnt(0)" ::: "memory"); }

  // ---- peeled first iteration (S-only) ----
  stageK(kt0);                                        // out: K(kt0)(4)  [+qf(8) older]
  stageV(kt0);                                        // out: +V(kt0)(8)
  asm volatile("s_waitcnt vmcnt(8)" ::: "memory");    // drains qf + K(kt0); V(kt0) flies
  SBARR();
  S_phase(kt0);
  if (kt0 + 1 <= ktmax) stageK(kt0 + 1);              // out: V(kt0)(8), K(kt0+1)(4)
  WLGKM0(); SBARR();

  // ---- main loop ----
  for (int kt = kt0 + 1; kt <= ktmax; ++kt) {
    asm volatile("s_waitcnt vmcnt(4)" ::: "memory");  // V(kt-1) landed; K(kt) flies
    SBARR();
    PV_phase(kt - 1);
    WLGKM0(); SBARR();                                // V buf + p[kt-1] free
    stageV(kt);                                       // out: K(kt)(4), V(kt)(8)
    asm volatile("s_waitcnt vmcnt(8)" ::: "memory");  // K(kt) landed; V(kt) flies
    SBARR();
    S_phase(kt);
    if (kt + 1 <= ktmax) stageK(kt + 1);              // out: V(kt)(8), K(kt+1)(4)
    WLGKM0(); SBARR();                                // p[kt] visible
  }

  // ---- epilogue PV(ktmax) ----
  asm volatile("s_waitcnt vmcnt(0)" ::: "memory");
  SBARR();
  PV_phase(ktmax);

  // RMS: wave has 128-dv partial for all 64 rows -> cross-wave combine via red
  __syncthreads();
#pragma unroll
  for (int rt = 0; rt < 4; rt++)
#pragma unroll
    for (int r = 0; r < 4; r++) {
      float s = 0.f;
#pragma unroll
      for (int n = 0; n < 8; n++) { float v = acc[rt][n][r]; s += v * v; }
      s += __shfl_xor(s, 1);
      s += __shfl_xor(s, 2);
      s += __shfl_xor(s, 4);
      s += __shfl_xor(s, 8);
      if (c16 == 0) red[(rt * 16 + quad * 4 + r) * 4 + w] = s;
    }
  __syncthreads();
  float ss[4][4];
#pragma unroll
  for (int rt = 0; rt < 4; rt++)
#pragma unroll
    for (int r = 0; r < 4; r++) {
      int row = rt * 16 + quad * 4 + r;
      float tot = red[row * 4] + red[row * 4 + 1] + red[row * 4 + 2] + red[row * 4 + 3];
      ss[rt][r] = rsqrtf(tot * (1.0f / DVv) + EPSf);
    }
  __syncthreads();

#pragma unroll
  for (int n = 0; n < 8; n++) {
    int col = w * 128 + n * 16 + c16;
    float gw = gnw[col];
#pragma unroll
    for (int rt = 0; rt < 4; rt++)
#pragma unroll
      for (int r = 0; r < 4; r++) {
        int row = rt * 16 + quad * 4 + r;
        o_lds[row * 512 + col] = __float2bfloat16(acc[rt][n][r] * ss[rt][r] * gw);
      }
  }
  __syncthreads();

#pragma unroll
  for (int it = 0; it < 16; it++) {
    int cid = it * 256 + tid;
    int row = cid >> 6;
    int cp = (cid & 63) * 8;
    const ushort_t* gp = (const ushort_t*)g + ((size_t)(b * Tn + q0 + row) * NH + h) * DVv + cp;
    us8 gv = *(const us8*)gp;
    us8 ov;
#pragma unroll
    for (int e = 0; e < 8; e++) {
      float gf = bf2f_raw(gv[e]);
      float gate = gf / (1.0f + expf(-gf));
      float of = __bfloat162float(o_lds[row * 512 + cp + e]);
      ov[e] = f2bf_raw(of * gate);
    }
    *(us8*)((ushort_t*)X + ((size_t)(b * Tn + q0 + row) * NH + h) * DVv + cp) = ov;
  }
}

extern "C" void kernel_launch(void* const* d_in, const int* in_sizes, int n_in,
                              void* d_out, int out_size, void* d_ws, size_t ws_size,
                              hipStream_t stream) {
  const float* hs  = (const float*)d_in[0];
  const float* Wq  = (const float*)d_in[1];
  const float* Wk  = (const float*)d_in[2];
  const float* Wv  = (const float*)d_in[3];
  const float* Wg  = (const float*)d_in[4];
  const float* Wo  = (const float*)d_in[5];
  const float* gnw = (const float*)d_in[6];
  float* out = (float*)d_out;
  char* ws = (char*)d_ws;

  bf16* hsb = (bf16*)(ws);                    // 16 MB
  bf16* WqT = (bf16*)(ws + 16777216);         //  8 MB  } contiguous [4096][2048] for fused qk
  bf16* WkT = (bf16*)(ws + 25165824);         //  8 MB  }
  bf16* WvT = (bf16*)(ws + 33554432);         // 16 MB  } contiguous [8192][2048] for fused vg
  bf16* WgT = (bf16*)(ws + 50331648);         // 16 MB  }
  char* vSb = ws;                              // alias hsb/WqT/WkT (dead after q/k/v/g GEMMs)
  bf16* WoT = (bf16*)(ws + 33554432);         // alias WvT (dead after vg GEMM)
  bf16* qb = (bf16*)(ws + 67108864);          // 16 MB
  bf16* kb = (bf16*)(ws + 83886080);          // 16 MB
  bf16* vb = (bf16*)(ws + 100663296);         // 32 MB
  bf16* gb = (bf16*)(ws + 134217728);         // 32 MB
  bf16* Xb = vb;                               // alias v (dead after vS build)
  float* p0 = (float*)ws;                      // 32 MB fp32 partial (alias vSb, dead after retention)
  float* p1 = (float*)(ws + 50331648);         // 32 MB fp32 partial (alias WgT+qb, dead after retention)

  static bool attr_done = false;
  if (!attr_done) {
    hipFuncSetAttribute((const void*)k_gemm8<false, false>, hipFuncAttributeMaxDynamicSharedMemorySize, 131072);
    hipFuncSetAttribute((const void*)k_gemm8<false, true>, hipFuncAttributeMaxDynamicSharedMemorySize, 131072);
    hipFuncSetAttribute((const void*)k_gemm8<true, false>, hipFuncAttributeMaxDynamicSharedMemorySize, 131072);
    hipFuncSetAttribute((const void*)k_retention, hipFuncAttributeMaxDynamicSharedMemorySize, 76800);
    attr_done = true;
  }

  k_f32_to_bf16<<<8192, 256, 0, stream>>>((const float4*)hs, (ushort4*)hsb, 2097152);
  k_transpose64<<<dim3(HID / 64, HID / 64), 256, 0, stream>>>(Wq, WqT, HID, HID);
  k_transpose64<<<dim3(HID / 64, HID / 64), 256, 0, stream>>>(Wk, WkT, HID, HID);
  k_transpose64<<<dim3(NH * DVv / 64, HID / 64), 256, 0, stream>>>(Wv, WvT, HID, NH * DVv);
  k_transpose64<<<dim3(NH * DVv / 64, HID / 64), 256, 0, stream>>>(Wg, WgT, HID, NH * DVv);
  // fused q|k GEMM with fused RoPE epilogue: q (scale 0.0625) -> qb, k -> kb
  k_gemm8<false, true><<<dim3(16, 16), 512, 131072, stream>>>(hsb, WqT, qb, kb, 2048, 4096, 4096, 2048, 2048);
  // fused v|g: C[4096][8192] = hsb @ [WvT|WgT]^T, split at n=4096 -> vb, gb
  k_gemm8<false, false><<<dim3(32, 16), 512, 131072, stream>>>(hsb, WvT, vb, gb, 4096, 4096, 8192, 2048, 2048);
  k_build_vS<<<dim3(64, 16), 256, 0, stream>>>((const ushort_t*)vb, (ushort_t*)vSb);
  k_transpose64<<<dim3(HID / 64, NH * DVv / 64), 256, 0, stream>>>(Wo, WoT, NH * DVv, HID);
  k_retention<<<512, 256, 76800, stream>>>(qb, kb, vSb, gb, gnw, Xb);
  // out-proj split-K=2 through the 8-phase kernel: 256 blocks (full GPU), fp32 partials + reduce
  k_gemm8<true, false><<<dim3(8, 16, 2), 512, 131072, stream>>>(Xb, WoT, p0, p1, 2048, 4096, 2048, 2048, 4096);
  k_add2_f32<<<8192, 256, 0, stream>>>((const float4*)p0, (const float4*)p1, (float4*)out, 2097152);
}

// Round 11
// 580.126 us; speedup vs baseline: 1.0484x; 1.0139x over previous
//
#include <hip/hip_runtime.h>
#include <hip/hip_bf16.h>
#include <math.h>

#define NH 8
#define DKk 256
#define DVv 512
#define Bn 2
#define Tn 2048
#define HID 2048
#define EPSf 1e-5f

typedef __bf16 bf16x8 __attribute__((ext_vector_type(8)));
typedef float f32x4 __attribute__((ext_vector_type(4)));
typedef unsigned short us8 __attribute__((ext_vector_type(8)));
using bf16 = __hip_bfloat16;
typedef unsigned short ushort_t;

__device__ __forceinline__ void gload_lds16(const void* g, void* lds_base) {
  __builtin_amdgcn_global_load_lds(
      (const __attribute__((address_space(1))) void*)g,
      (__attribute__((address_space(3))) void*)lds_base, 16, 0, 0);
}

__device__ __forceinline__ ushort_t f2bf_raw(float f) {
  bf16 h = __float2bfloat16(f);
  return *reinterpret_cast<ushort_t*>(&h);
}
__device__ __forceinline__ float bf2f_raw(ushort_t u) {
  union { unsigned int i; float f; } v; v.i = ((unsigned int)u) << 16; return v.f;
}

// ---------------- fp32 -> bf16 elementwise (vectorized x4) ----------------
__global__ void k_f32_to_bf16(const float4* __restrict__ in, ushort4* __restrict__ out, int n4) {
  int i = blockIdx.x * blockDim.x + threadIdx.x;
  if (i >= n4) return;
  float4 v = in[i];
  ushort4 o;
  o.x = f2bf_raw(v.x); o.y = f2bf_raw(v.y); o.z = f2bf_raw(v.z); o.w = f2bf_raw(v.w);
  out[i] = o;
}

// ---------------- fp32 a + b -> out (vectorized x4), split-K reduce ----------------
__global__ void k_add2_f32(const float4* __restrict__ a, const float4* __restrict__ b,
                           float4* __restrict__ o, int n4) {
  int i = blockIdx.x * blockDim.x + threadIdx.x;
  if (i >= n4) return;
  float4 x = a[i], y = b[i];
  float4 r; r.x = x.x + y.x; r.y = x.y + y.y; r.z = x.z + y.z; r.w = x.w + y.w;
  o[i] = r;
}

// ---------------- W (K,N) fp32 -> WT (N,K) bf16, 64x64 tile ----------------
__global__ __launch_bounds__(256) void k_transpose64(const float* __restrict__ W, bf16* __restrict__ WT,
                                                     int K, int N) {
  __shared__ unsigned int t32[64 * 33];  // 8448 B
  const int tid = threadIdx.x;
  const int n0 = blockIdx.x * 64, k0 = blockIdx.y * 64;
  const int a = tid >> 3;    // 0..31 row-pair
  const int bq = tid & 7;    // 0..7  col-chunk (8 cols)

  const float* r0 = W + (size_t)(k0 + 2 * a) * N + n0 + bq * 8;
  const float* r1 = r0 + N;
  float4 v00 = *(const float4*)r0;
  float4 v01 = *(const float4*)(r0 + 4);
  float4 v10 = *(const float4*)r1;
  float4 v11 = *(const float4*)(r1 + 4);
  float e0[8] = {v00.x, v00.y, v00.z, v00.w, v01.x, v01.y, v01.z, v01.w};
  float e1[8] = {v10.x, v10.y, v10.z, v10.w, v11.x, v11.y, v11.z, v11.w};
#pragma unroll
  for (int j = 0; j < 8; j++) {
    unsigned int val = (unsigned int)f2bf_raw(e0[j]) | ((unsigned int)f2bf_raw(e1[j]) << 16);
    t32[(bq * 8 + j) * 33 + a] = val;
  }
  __syncthreads();
  const int nl = tid >> 2, part = tid & 3;
  unsigned int c[8];
#pragma unroll
  for (int i = 0; i < 8; i++) c[i] = t32[nl * 33 + part * 8 + i];
  char* dst = (char*)(WT + (size_t)(n0 + nl) * K + k0 + part * 16);
  uint4 lo; lo.x = c[0]; lo.y = c[1]; lo.z = c[2]; lo.w = c[3];
  uint4 hi; hi.x = c[4]; hi.y = c[5]; hi.z = c[6]; hi.w = c[7];
  *(uint4*)dst = lo;
  *(uint4*)(dst + 16) = hi;
}

// ================= 256x256 8-phase GEMM, v3 (R5/R7-measured best: 45.6% MfmaUtil) ==========
// Schedule is a MEASURED LOCAL OPTIMUM — R6 counted-lgkm: −9%; R8 deep-slack: −5%. Do not
// perturb without within-probe A/B. Epilogue MODEs:
//   1 = split-K fp32 partials via blockIdx.z (O0/O1 + k_add2_f32 reduce)
//   2 = fused RoPE (qk): LDS-stage tile, rotate (i, i+128), q-scale folded, write q/k
//   3 = fused vS build (vg): v-half LDS-stage tile then emit vS 16B units directly
//       (replaces k_build_vS: saves 64MB round-trip + 1 dispatch); g-half normal bf16
//   0 = dual bf16 split at nsplit
#define BARX() asm volatile("s_barrier" ::: "memory")
#define LGKM0() { asm volatile("s_waitcnt lgkmcnt(0)" ::: "memory"); __builtin_amdgcn_sched_barrier(0); }
#define VMW4() asm volatile("s_waitcnt vmcnt(4)" ::: "memory")
#define VMW0() asm volatile("s_waitcnt vmcnt(0)" ::: "memory")
#define PRIO1 __builtin_amdgcn_s_setprio(1)
#define PRIO0 __builtin_amdgcn_s_setprio(0)

#define QUADQ(MB, NB)                                                              \
  { _Pragma("unroll") for (int kk_ = 0; kk_ < 2; ++kk_)                            \
    _Pragma("unroll") for (int mf_ = 0; mf_ < 4; ++mf_)                            \
    _Pragma("unroll") for (int nf_ = 0; nf_ < 2; ++nf_)                            \
      acc[(MB) + mf_][(NB) + nf_] = __builtin_amdgcn_mfma_f32_16x16x32_bf16(       \
          ar[(MB) + mf_][kk_], br[(NB) + nf_][kk_],                                \
          acc[(MB) + mf_][(NB) + nf_], 0, 0, 0); }

template <int MODE>
__global__ __launch_bounds__(512, 2) void k_gemm8(const bf16* __restrict__ A, const bf16* __restrict__ BT,
                                                  void* __restrict__ O0, void* __restrict__ O1,
                                                  int nsplit, int M, int Ntot, int Kloop, int Kstride) {
  extern __shared__ char lds[];
  const int tid = threadIdx.x;
  const int lane = tid & 63;
  const int w = tid >> 6;        // 0..7
  const int wr = w >> 2;         // 0..1 (M half)
  const int wc = w & 3;          // 0..3 (N quarter)
  const int quad = lane >> 4, c16 = lane & 15;
  const int m0 = blockIdx.y * 256, n0 = blockIdx.x * 256;
  const int ks = blockIdx.z;

  const bf16* Ab = A + (size_t)ks * Kloop;
  const bf16* Bb = BT + (size_t)ks * Kloop;

  const int srow = (w << 4) | (lane >> 3);
  const int gsw = (((lane & 7) ^ (lane >> 3)) << 4);   // inverse-swizzled source granule
  const size_t rowBytes = (size_t)Kstride * 2;
  const char* aS = (const char*)(Ab + (size_t)(m0 + srow) * Kstride) + gsw;
  const char* bS = (const char*)(Bb + (size_t)(n0 + srow) * Kstride) + gsw;

  auto stage = [&](int matB, int buf, int h, int t) {
    const char* base = (matB ? bS : aS) + (size_t)h * 128 * rowBytes + (size_t)t * 128;
    char* ldst = lds + buf * 65536 + matB * 32768 + h * 16384 + w * 2048;
    gload_lds16(base, ldst);
    gload_lds16(base + 8 * rowBytes, ldst + 1024);
  };
  auto ldA = [&](int buf, int mf, int kk) -> bf16x8 {
    int row = wr * 128 + mf * 16 + c16;
    return *(const bf16x8*)(lds + buf * 65536 + row * 128 + ((((kk << 2) | quad) ^ (c16 & 7)) << 4));
  };
  auto ldB = [&](int buf, int nf, int kk) -> bf16x8 {
    int row = wc * 64 + nf * 16 + c16;
    return *(const bf16x8*)(lds + buf * 65536 + 32768 + row * 128 + ((((kk << 2) | quad) ^ (c16 & 7)) << 4));
  };

  f32x4 acc[8][4];
  const f32x4 fz = {0.f, 0.f, 0.f, 0.f};
#pragma unroll
  for (int i = 0; i < 8; i++)
#pragma unroll
    for (int j = 0; j < 4; j++) acc[i][j] = fz;
  bf16x8 ar[8][2], br[4][2];

  const int nT = Kloop >> 6;
  const int nIter = nT >> 1;

  // prologue: tile0 full + tile1 A -> 12 loads; vmcnt(4) leaves t1.A in flight
  stage(0, 0, 0, 0); stage(0, 0, 1, 0);
  stage(1, 0, 0, 0); stage(1, 0, 1, 0);
  stage(0, 1, 0, 1); stage(0, 1, 1, 1);
  VMW4();
  BARX();

  for (int it = 0; it < nIter; ++it) {
    const int t = it * 2;
    const bool last = (it == nIter - 1);
    // ---- ph1: ds A0-3 + B01 (buf0); stage (t+1)B0; Q00 ----
#pragma unroll
    for (int mf = 0; mf < 4; ++mf) { ar[mf][0] = ldA(0, mf, 0); ar[mf][1] = ldA(0, mf, 1); }
#pragma unroll
    for (int nf = 0; nf < 2; ++nf) { br[nf][0] = ldB(0, nf, 0); br[nf][1] = ldB(0, nf, 1); }
    stage(1, 1, 0, t + 1);
    BARX(); LGKM0();
    PRIO1; QUADQ(0, 0); PRIO0;
    BARX();
    // ---- ph2: ds A4-7 (buf0); stage (t+1)B1; Q10 ----
#pragma unroll
    for (int mf = 4; mf < 8; ++mf) { ar[mf][0] = ldA(0, mf, 0); ar[mf][1] = ldA(0, mf, 1); }
    stage(1, 1, 1, t + 1);
    BARX(); LGKM0();
    PRIO1; QUADQ(4, 0); PRIO0;
    BARX();
    // ---- ph3: ds B23 (buf0); stage (t+2)A0; Q01 ----
#pragma unroll
    for (int nf = 2; nf < 4; ++nf) { br[nf][0] = ldB(0, nf, 0); br[nf][1] = ldB(0, nf, 1); }
    if (!last) stage(0, 0, 0, t + 2);
    BARX(); LGKM0();
    PRIO1; QUADQ(0, 2); PRIO0;
    BARX();
    // ---- ph4: stage (t+2)A1; Q11; vmcnt(4) -> tile t+1 landed ----
    if (!last) stage(0, 0, 1, t + 2);
    BARX();
    PRIO1; QUADQ(4, 2); PRIO0;
    if (!last) { VMW4(); } else { VMW0(); }
    BARX();
    // ---- ph5: ds A0-3 + B01 (buf1); stage (t+2)B0; Q00 ----
#pragma unroll
    for (int mf = 0; mf < 4; ++mf) { ar[mf][0] = ldA(1, mf, 0); ar[mf][1] = ldA(1, mf, 1); }
#pragma unroll
    for (int nf = 0; nf < 2; ++nf) { br[nf][0] = ldB(1, nf, 0); br[nf][1] = ldB(1, nf, 1); }
    if (!last) stage(1, 0, 0, t + 2);
    BARX(); LGKM0();
    PRIO1; QUADQ(0, 0); PRIO0;
    BARX();
    // ---- ph6: ds A4-7 (buf1); stage (t+2)B1; Q10 ----
#pragma unroll
    for (int mf = 4; mf < 8; ++mf) { ar[mf][0] = ldA(1, mf, 0); ar[mf][1] = ldA(1, mf, 1); }
    if (!last) stage(1, 0, 1, t + 2);
    BARX(); LGKM0();
    PRIO1; QUADQ(4, 0); PRIO0;
    BARX();
    // ---- ph7: ds B23 (buf1); stage (t+3)A0; Q01 ----
#pragma unroll
    for (int nf = 2; nf < 4; ++nf) { br[nf][0] = ldB(1, nf, 0); br[nf][1] = ldB(1, nf, 1); }
    if (!last) stage(0, 1, 0, t + 3);
    BARX(); LGKM0();
    PRIO1; QUADQ(0, 2); PRIO0;
    BARX();
    // ---- ph8: stage (t+3)A1; Q11; vmcnt(4) ----
    if (!last) stage(0, 1, 1, t + 3);
    BARX();
    PRIO1; QUADQ(4, 2); PRIO0;
    if (!last) VMW4();
    BARX();
  }

  if (MODE == 2) {
    // ---- fused RoPE epilogue: tile -> LDS [256 m][256 i] bf16 (128KB, exact fit) ----
    __syncthreads();   // all main-loop LDS reads complete before overwrite
    ushort_t* tile = (ushort_t*)lds;
#pragma unroll
    for (int mf = 0; mf < 8; ++mf)
#pragma unroll
      for (int nf = 0; nf < 4; ++nf)
#pragma unroll
        for (int rr = 0; rr < 4; ++rr) {
          int row = wr * 128 + mf * 16 + quad * 4 + rr;
          int col = wc * 64 + nf * 16 + c16;
          tile[row * 256 + col] = f2bf_raw(acc[mf][nf][rr]);
        }
    __syncthreads();
    const bool qside = (n0 < nsplit);
    bf16* Ob = (bf16*)(qside ? O0 : O1);
    const float scale = qside ? 0.0625f : 1.0f;
    const int h = (qside ? n0 : n0 - nsplit) >> 8;   // 256-col tile == exactly one head
#pragma unroll
    for (int j = 0; j < 8; ++j) {
      int u = j * 512 + tid;
      int row = u >> 4;
      int ch = u & 15;
      const ushort_t* lp = tile + row * 256 + ch * 8;
      us8 lo = *(const us8*)lp;
      us8 hi = *(const us8*)(lp + 128);
      int m = m0 + row;                       // m = b*Tn + t
      float tf = (float)(m & (Tn - 1));       // t within sequence
      us8 olo, ohi;
#pragma unroll
      for (int e = 0; e < 8; ++e) {
        int i = ch * 8 + e;
        float inv = exp2f(-(float)i * (13.287712379549449f / 128.0f));
        float ang = tf * inv;
        float s, c;
        sincosf(ang, &s, &c);
        float x1 = bf2f_raw(lo[e]);
        float x2 = bf2f_raw(hi[e]);
        olo[e] = f2bf_raw((x1 * c - x2 * s) * scale);
        ohi[e] = f2bf_raw((x2 * c + x1 * s) * scale);
      }
      ushort_t* dst = (ushort_t*)Ob + ((size_t)m * NH + h) * DKk + ch * 8;
      *(us8*)dst = olo;
      *(us8*)(dst + 128) = ohi;
    }
  } else if (MODE == 1) {
    // split-K fp32 partial: z selects buffer, full N width
    float* Ob = (float*)(ks ? O1 : O0);
#pragma unroll
    for (int mf = 0; mf < 8; ++mf)
#pragma unroll
      for (int nf = 0; nf < 4; ++nf)
#pragma unroll
        for (int rr = 0; rr < 4; ++rr) {
          int m = m0 + wr * 128 + mf * 16 + quad * 4 + rr;
          int n = n0 + wc * 64 + nf * 16 + c16;
          Ob[(size_t)m * Ntot + n] = acc[mf][nf][rr];
        }
  } else if (MODE == 3 && n0 < nsplit) {
    // ---- fused vS-build epilogue (v-half): tile -> LDS [256 t][256 dv], emit 16B units ----
    // unit (bh,kt,chunk,dv)[jj] = v[t = kt*32 + chunk*8 + jj][dv]  (matches old k_build_vS)
    __syncthreads();
    ushort_t* tile = (ushort_t*)lds;
#pragma unroll
    for (int mf = 0; mf < 8; ++mf)
#pragma unroll
      for (int nf = 0; nf < 4; ++nf)
#pragma unroll
        for (int rr = 0; rr < 4; ++rr) {
          int row = wr * 128 + mf * 16 + quad * 4 + rr;
          int col = wc * 64 + nf * 16 + c16;
          tile[row * 256 + col] = f2bf_raw(acc[mf][nf][rr]);
        }
    __syncthreads();
    const int b = m0 >> 11;                   // m = b*2048 + t
    const int kt0 = (m0 & 2047) >> 5;         // tile spans kt0..kt0+7
    const int h = n0 >> 9;                    // n = h*512 + dv
    const int dv0 = n0 & 511;                 // 0 or 256
    const int bh = b * 8 + h;
    ushort_t* vSo = (ushort_t*)O0;
    // u = uu*512+tid: ktl=u>>10, chunk=(u>>8)&3, dvl=u&255. Lanes: consecutive dvl ->
    // LDS reads conflict-free (consecutive u16), stores 16B/lane fully coalesced.
#pragma unroll
    for (int uu = 0; uu < 16; ++uu) {
      int u = uu * 512 + tid;
      int ktl = u >> 10;
      int chunk = (u >> 8) & 3;
      int dvl = u & 255;
      us8 o;
#pragma unroll
      for (int jj = 0; jj < 8; ++jj)
        o[jj] = tile[(ktl * 32 + chunk * 8 + jj) * 256 + dvl];
      *(us8*)(vSo + ((size_t)(bh * 64 + kt0 + ktl) * 2048 + chunk * 512 + (dv0 + dvl)) * 8) = o;
    }
  } else {
    // dual bf16 outputs split at n = nsplit (MODE 0, or MODE 3 g-half)
    bf16* Ob; int ldo, nc0;
    if (n0 < nsplit) { Ob = (bf16*)O0; ldo = nsplit; nc0 = n0; }
    else             { Ob = (bf16*)O1; ldo = Ntot - nsplit; nc0 = n0 - nsplit; }
#pragma unroll
    for (int mf = 0; mf < 8; ++mf)
#pragma unroll
      for (int nf = 0; nf < 4; ++nf)
#pragma unroll
        for (int rr = 0; rr < 4; ++rr) {
          int m = m0 + wr * 128 + mf * 16 + quad * 4 + rr;
          int n = nc0 + wc * 64 + nf * 16 + c16;
          Ob[(size_t)m * ldo + n] = __float2bfloat16(acc[mf][nf][rr]);
        }
  }
}

// ---------------- Retention v4 (R5/R7-measured best): rotated loop {PV(t-1); S(t)} ----------------
// K-dbuf + V-sbuf + P-dbuf, LDS 76.8KB -> 2 blocks/CU + counted-vmcnt pipelining.
// Ledger verified in R4/R5. (v5 swapped-S + shfl redistribute regressed in R6 — do not reapply.)
__global__ __launch_bounds__(256, 2) void k_retention(const bf16* __restrict__ q, const bf16* __restrict__ k,
                                                      const char* __restrict__ vS, const bf16* __restrict__ g,
                                                      const float* __restrict__ gnw, bf16* __restrict__ X) {
  extern __shared__ char smem[];
  ushort_t* p_lds_base = (ushort_t*)(smem + 65536);
  float* red = (float*)(smem + 75776);
  bf16* o_lds = (bf16*)smem;   // epilogue alias (64KB)

  const int tid = threadIdx.x;
  const int l = tid & 63, w = tid >> 6;
  const int quad = l >> 4, c16 = l & 15;

  const int bid = blockIdx.x;
  const int u = (bid & 255) >> 4;
  const int qt = (bid < 256) ? (31 - u) : u;   // heavy half then light half
  const int bh = bid & 15;
  const int b = bh >> 3, h = bh & 7;
  const int q0 = qt * 64;

  bf16x8 qf[8];
  {
    const bf16* qrow = q + ((size_t)(b * Tn + q0 + w * 16 + c16) * NH + h) * DKk + quad * 8;
#pragma unroll
    for (int c = 0; c < 8; c++) qf[c] = *(const bf16x8*)(qrow + c * 32);
  }

  const float log2g = log2f(1.0f - exp2f(-5.0f - (float)h));

  f32x4 acc[4][8];
  const f32x4 fz = {0.f, 0.f, 0.f, 0.f};
#pragma unroll
  for (int rt = 0; rt < 4; rt++)
#pragma unroll
    for (int n = 0; n < 8; n++) acc[rt][n] = fz;

  const int ktmax = 2 * qt + 1;
  const float Dcut = 30.0f / (-log2g);
  int kt0 = (int)fmaxf(0.0f, floorf(((float)q0 - Dcut) * (1.0f / 32.0f)));

  const char* vS_tilebase = vS + (size_t)(bh * 64) * 32768;

  auto stageK = [&](int kt) {
    const int pb = (kt - kt0) & 1;
#pragma unroll
    for (int i = 0; i < 4; i++) {
      int instr = w * 4 + i;
      int j = instr * 2 + (l >> 5);
      int cg = (l & 31) ^ (j & 7);
      const char* gp = (const char*)(k + ((size_t)(b * Tn + kt * 32 + j) * NH + h) * DKk) + cg * 16;
      gload_lds16(gp, smem + pb * 16384 + instr * 1024);
    }
  };
  auto stageV = [&](int kt) {
#pragma unroll
    for (int i = 0; i < 8; i++) {
      int instr = w * 8 + i;
      const char* gp = vS_tilebase + (size_t)kt * 32768 + instr * 1024 + l * 16;
      gload_lds16(gp, smem + 32768 + instr * 1024);
    }
  };

  auto S_phase = [&](int kt) {
    const int pb = (kt - kt0) & 1;
    f32x4 sacc[2] = {fz, fz};
#pragma unroll
    for (int jt = 0; jt < 2; jt++)
#pragma unroll
      for (int c = 0; c < 8; c++) {
        const char* kp = smem + pb * 16384 + (jt * 16 + c16) * 512 + (((c * 4 + quad) ^ (c16 & 7)) * 16);
        bf16x8 bfrag = *(const bf16x8*)kp;
        sacc[jt] = __builtin_amdgcn_mfma_f32_16x16x32_bf16(qf[c], bfrag, sacc[jt], 0, 0, 0);
      }
    ushort_t* pbuf = p_lds_base + pb * 2560;
#pragma unroll
    for (int jt = 0; jt < 2; jt++)
#pragma unroll
      for (int r = 0; r < 4; r++) {
        int ig = q0 + w * 16 + quad * 4 + r;
        int jg = kt * 32 + jt * 16 + c16;
        int d = ig - jg;
        float val = (d >= 0) ? sacc[jt][r] * exp2f(log2g * (float)d) : 0.0f;
        pbuf[(w * 16 + quad * 4 + r) * 40 + jt * 16 + c16] = f2bf_raw(val);
      }
  };

  auto PV_phase = [&](int kt) {
    const int pb = (kt - kt0) & 1;
    const char* pbuf = (const char*)(p_lds_base + pb * 2560);
    bf16x8 pa[4];
#pragma unroll
    for (int rt = 0; rt < 4; rt++)
      pa[rt] = *(const bf16x8*)(pbuf + (rt * 16 + c16) * 80 + quad * 16);
    const char* v_lds = smem + 32768;
#pragma unroll
    for (int n = 0; n < 8; n++) {
      bf16x8 bv = *(const bf16x8*)(v_lds + quad * 8192 + (w * 128 + n * 16 + c16) * 16);
#pragma unroll
      for (int rt = 0; rt < 4; rt++)
        acc[rt][n] = __builtin_amdgcn_mfma_f32_16x16x32_bf16(pa[rt], bv, acc[rt][n], 0, 0, 0);
    }
  };

#define SBARR() { __builtin_amdgcn_sched_barrier(0); __builtin_amdgcn_s_barrier(); }
#define WLGKM0() { asm volatile("s_waitcnt lgkmcnt(0)" ::: "memory"); }

  // ---- peeled first iteration (S-only) ----
  stageK(kt0);                                        // out: K(kt0)(4)  [+qf(8) older]
  stageV(kt0);                                        // out: +V(kt0)(8)
  asm volatile("s_waitcnt vmcnt(8)" ::: "memory");    // drains qf + K(kt0); V(kt0) flies
  SBARR();
  S_phase(kt0);
  if (kt0 + 1 <= ktmax) stageK(kt0 + 1);              // out: V(kt0)(8), K(kt0+1)(4)
  WLGKM0(); SBARR();

  // ---- main loop ----
  for (int kt = kt0 + 1; kt <= ktmax; ++kt) {
    asm volatile("s_waitcnt vmcnt(4)" ::: "memory");  // V(kt-1) landed; K(kt) flies
    SBARR();
    PV_phase(kt - 1);
    WLGKM0(); SBARR();                                // V buf + p[kt-1] free
    stageV(kt);                                       // out: K(kt)(4), V(kt)(8)
    asm volatile("s_waitcnt vmcnt(8)" ::: "memory");  // K(kt) landed; V(kt) flies
    SBARR();
    S_phase(kt);
    if (kt + 1 <= ktmax) stageK(kt + 1);              // out: V(kt)(8), K(kt+1)(4)
    WLGKM0(); SBARR();                                // p[kt] visible
  }

  // ---- epilogue PV(ktmax) ----
  asm volatile("s_waitcnt vmcnt(0)" ::: "memory");
  SBARR();
  PV_phase(ktmax);

  // RMS: wave has 128-dv partial for all 64 rows -> cross-wave combine via red
  __syncthreads();
#pragma unroll
  for (int rt = 0; rt < 4; rt++)
#pragma unroll
    for (int r = 0; r < 4; r++) {
      float s = 0.f;
#pragma unroll
      for (int n = 0; n < 8; n++) { float v = acc[rt][n][r]; s += v * v; }
      s += __shfl_xor(s, 1);
      s += __shfl_xor(s, 2);
      s += __shfl_xor(s, 4);
      s += __shfl_xor(s, 8);
      if (c16 == 0) red[(rt * 16 + quad * 4 + r) * 4 + w] = s;
    }
  __syncthreads();
  float ss[4][4];
#pragma unroll
  for (int rt = 0; rt < 4; rt++)
#pragma unroll
    for (int r = 0; r < 4; r++) {
      int row = rt * 16 + quad * 4 + r;
      float tot = red[row * 4] + red[row * 4 + 1] + red[row * 4 + 2] + red[row * 4 + 3];
      ss[rt][r] = rsqrtf(tot * (1.0f / DVv) + EPSf);
    }
  __syncthreads();

#pragma unroll
  for (int n = 0; n < 8; n++) {
    int col = w * 128 + n * 16 + c16;
    float gw = gnw[col];
#pragma unroll
    for (int rt = 0; rt < 4; rt++)
#pragma unroll
      for (int r = 0; r < 4; r++) {
        int row = rt * 16 + quad * 4 + r;
        o_lds[row * 512 + col] = __float2bfloat16(acc[rt][n][r] * ss[rt][r] * gw);
      }
  }
  __syncthreads();

#pragma unroll
  for (int it = 0; it < 16; it++) {
    int cid = it * 256 + tid;
    int row = cid >> 6;
    int cp = (cid & 63) * 8;
    const ushort_t* gp = (const ushort_t*)g + ((size_t)(b * Tn + q0 + row) * NH + h) * DVv + cp;
    us8 gv = *(const us8*)gp;
    us8 ov;
#pragma unroll
    for (int e = 0; e < 8; e++) {
      float gf = bf2f_raw(gv[e]);
      float gate = gf / (1.0f + expf(-gf));
      float of = __bfloat162float(o_lds[row * 512 + cp + e]);
      ov[e] = f2bf_raw(of * gate);
    }
    *(us8*)((ushort_t*)X + ((size_t)(b * Tn + q0 + row) * NH + h) * DVv + cp) = ov;
  }
}

extern "C" void kernel_launch(void* const* d_in, const int* in_sizes, int n_in,
                              void* d_out, int out_size, void* d_ws, size_t ws_size,
                              hipStream_t stream) {
  const float* hs  = (const float*)d_in[0];
  const float* Wq  = (const float*)d_in[1];
  const float* Wk  = (const float*)d_in[2];
  const float* Wv  = (const float*)d_in[3];
  const float* Wg  = (const float*)d_in[4];
  const float* Wo  = (const float*)d_in[5];
  const float* gnw = (const float*)d_in[6];
  float* out = (float*)d_out;
  char* ws = (char*)d_ws;

  // Workspace map (re-audited for R11 vS fusion — vg GEMM now WRITES vS, so vS must not
  // alias anything vg reads):
  //   hsb 0..16MB | WqT 16..24 | WkT 24..32 | WvT 32..48 | WgT 48..64
  //   qb 64..80 | kb 80..96 | vSb 96..128 (written by vg epilogue) | gb 128..160
  //   WoT 32..48 (alias WvT, after vg) | Xb 0..32 (alias hsb/WqT/WkT, retention out)
  //   p0 48..80 (alias WgT+qb, dead at out-proj) | p1 80..112 (alias kb+vS-head, dead)
  bf16* hsb = (bf16*)(ws);
  bf16* WqT = (bf16*)(ws + 16777216);
  bf16* WkT = (bf16*)(ws + 25165824);
  bf16* WvT = (bf16*)(ws + 33554432);
  bf16* WgT = (bf16*)(ws + 50331648);
  bf16* qb  = (bf16*)(ws + 67108864);
  bf16* kb  = (bf16*)(ws + 83886080);
  char* vSb = ws + 100663296;
  bf16* gb  = (bf16*)(ws + 134217728);
  bf16* WoT = (bf16*)(ws + 33554432);
  bf16* Xb  = (bf16*)ws;
  float* p0 = (float*)(ws + 50331648);
  float* p1 = (float*)(ws + 83886080);

  static bool attr_done = false;
  if (!attr_done) {
    hipFuncSetAttribute((const void*)k_gemm8<1>, hipFuncAttributeMaxDynamicSharedMemorySize, 131072);
    hipFuncSetAttribute((const void*)k_gemm8<2>, hipFuncAttributeMaxDynamicSharedMemorySize, 131072);
    hipFuncSetAttribute((const void*)k_gemm8<3>, hipFuncAttributeMaxDynamicSharedMemorySize, 131072);
    hipFuncSetAttribute((const void*)k_retention, hipFuncAttributeMaxDynamicSharedMemorySize, 76800);
    attr_done = true;
  }

  k_f32_to_bf16<<<8192, 256, 0, stream>>>((const float4*)hs, (ushort4*)hsb, 2097152);
  k_transpose64<<<dim3(HID / 64, HID / 64), 256, 0, stream>>>(Wq, WqT, HID, HID);
  k_transpose64<<<dim3(HID / 64, HID / 64), 256, 0, stream>>>(Wk, WkT, HID, HID);
  k_transpose64<<<dim3(NH * DVv / 64, HID / 64), 256, 0, stream>>>(Wv, WvT, HID, NH * DVv);
  k_transpose64<<<dim3(NH * DVv / 64, HID / 64), 256, 0, stream>>>(Wg, WgT, HID, NH * DVv);
  // fused q|k GEMM with fused RoPE epilogue: q (scale 0.0625) -> qb, k -> kb
  k_gemm8<2><<<dim3(16, 16), 512, 131072, stream>>>(hsb, WqT, qb, kb, 2048, 4096, 4096, 2048, 2048);
  // fused v|g GEMM: v-half writes vS layout directly (replaces k_build_vS), g-half -> gb
  k_gemm8<3><<<dim3(32, 16), 512, 131072, stream>>>(hsb, WvT, vSb, gb, 4096, 4096, 8192, 2048, 2048);
  k_transpose64<<<dim3(HID / 64, NH * DVv / 64), 256, 0, stream>>>(Wo, WoT, NH * DVv, HID);
  k_retention<<<512, 256, 76800, stream>>>(qb, kb, vSb, gb, gnw, Xb);
  // out-proj split-K=2 through the 8-phase kernel: 256 blocks (full GPU), fp32 partials + reduce
  k_gemm8<1><<<dim3(8, 16, 2), 512, 131072, stream>>>(Xb, WoT, p0, p1, 2048, 4096, 2048, 2048, 4096);
  k_add2_f32<<<8192, 256, 0, stream>>>((const float4*)p0, (const float4*)p1, (float4*)out, 2097152);
}

// Round 12
// 565.309 us; speedup vs baseline: 1.0759x; 1.0262x over previous
//
#include <hip/hip_runtime.h>
#include <hip/hip_bf16.h>
#include <math.h>

#define NH 8
#define DKk 256
#define DVv 512
#define Bn 2
#define Tn 2048
#define HID 2048
#define EPSf 1e-5f

typedef __bf16 bf16x8 __attribute__((ext_vector_type(8)));
typedef float f32x4 __attribute__((ext_vector_type(4)));
typedef unsigned short us8 __attribute__((ext_vector_type(8)));
using bf16 = __hip_bfloat16;
typedef unsigned short ushort_t;

__device__ __forceinline__ void gload_lds16(const void* g, void* lds_base) {
  __builtin_amdgcn_global_load_lds(
      (const __attribute__((address_space(1))) void*)g,
      (__attribute__((address_space(3))) void*)lds_base, 16, 0, 0);
}

__device__ __forceinline__ ushort_t f2bf_raw(float f) {
  bf16 h = __float2bfloat16(f);
  return *reinterpret_cast<ushort_t*>(&h);
}
__device__ __forceinline__ float bf2f_raw(ushort_t u) {
  union { unsigned int i; float f; } v; v.i = ((unsigned int)u) << 16; return v.f;
}

// ---------------- fp32 a + b -> out (vectorized x4), split-K reduce ----------------
__global__ void k_add2_f32(const float4* __restrict__ a, const float4* __restrict__ b,
                           float4* __restrict__ o, int n4) {
  int i = blockIdx.x * blockDim.x + threadIdx.x;
  if (i >= n4) return;
  float4 x = a[i], y = b[i];
  float4 r; r.x = x.x + y.x; r.y = x.y + y.y; r.z = x.z + y.z; r.w = x.w + y.w;
  o[i] = r;
}

// ---------------- transpose64 body as device fn: W (K,N) fp32 -> WT (N,K) bf16 ----------------
__device__ __forceinline__ void transpose64_body(const float* __restrict__ W, bf16* __restrict__ WT,
                                                 int K, int N, int bx, int by, int tid,
                                                 unsigned int* t32 /* [64*33] shared */) {
  const int n0 = bx * 64, k0 = by * 64;
  const int a = tid >> 3;    // 0..31 row-pair
  const int bq = tid & 7;    // 0..7  col-chunk (8 cols)

  const float* r0 = W + (size_t)(k0 + 2 * a) * N + n0 + bq * 8;
  const float* r1 = r0 + N;
  float4 v00 = *(const float4*)r0;
  float4 v01 = *(const float4*)(r0 + 4);
  float4 v10 = *(const float4*)r1;
  float4 v11 = *(const float4*)(r1 + 4);
  float e0[8] = {v00.x, v00.y, v00.z, v00.w, v01.x, v01.y, v01.z, v01.w};
  float e1[8] = {v10.x, v10.y, v10.z, v10.w, v11.x, v11.y, v11.z, v11.w};
#pragma unroll
  for (int j = 0; j < 8; j++) {
    unsigned int val = (unsigned int)f2bf_raw(e0[j]) | ((unsigned int)f2bf_raw(e1[j]) << 16);
    t32[(bq * 8 + j) * 33 + a] = val;
  }
  __syncthreads();
  const int nl = tid >> 2, part = tid & 3;
  unsigned int c[8];
#pragma unroll
  for (int i = 0; i < 8; i++) c[i] = t32[nl * 33 + part * 8 + i];
  char* dst = (char*)(WT + (size_t)(n0 + nl) * K + k0 + part * 16);
  uint4 lo; lo.x = c[0]; lo.y = c[1]; lo.z = c[2]; lo.w = c[3];
  uint4 hi; hi.x = c[4]; hi.y = c[5]; hi.z = c[6]; hi.w = c[7];
  *(uint4*)dst = lo;
  *(uint4*)(dst + 16) = hi;
}

// ---------------- fused prep: hs cast (blocks 0..8191) + 5 weight transposes ----------------
// Block ranges: cast 8192 | Wq 1024 (32x32) | Wk 1024 | Wv 2048 (64x32) | Wg 2048 | Wo 2048 (32x64)
__global__ __launch_bounds__(256) void k_prep(const float* __restrict__ hs, ushort4* __restrict__ hsb4,
                                              const float* __restrict__ Wq, const float* __restrict__ Wk,
                                              const float* __restrict__ Wv, const float* __restrict__ Wg,
                                              const float* __restrict__ Wo,
                                              bf16* __restrict__ WqT, bf16* __restrict__ WkT,
                                              bf16* __restrict__ WvT, bf16* __restrict__ WgT,
                                              bf16* __restrict__ WoT) {
  __shared__ unsigned int t32[64 * 33];
  const int bid = blockIdx.x;
  const int tid = threadIdx.x;
  if (bid < 8192) {
    int i = bid * 256 + tid;   // n4 = 2097152 = 8192*256 exactly
    float4 v = ((const float4*)hs)[i];
    ushort4 o;
    o.x = f2bf_raw(v.x); o.y = f2bf_raw(v.y); o.z = f2bf_raw(v.z); o.w = f2bf_raw(v.w);
    hsb4[i] = o;
    return;
  }
  int t = bid - 8192;
  if (t < 1024)      transpose64_body(Wq, WqT, HID, HID, t & 31, t >> 5, tid, t32);
  else if (t < 2048) { t -= 1024; transpose64_body(Wk, WkT, HID, HID, t & 31, t >> 5, tid, t32); }
  else if (t < 4096) { t -= 2048; transpose64_body(Wv, WvT, HID, NH * DVv, t & 63, t >> 6, tid, t32); }
  else if (t < 6144) { t -= 4096; transpose64_body(Wg, WgT, HID, NH * DVv, t & 63, t >> 6, tid, t32); }
  else               { t -= 6144; transpose64_body(Wo, WoT, NH * DVv, HID, t & 31, t >> 5, tid, t32); }
}

// ================= 256x256 8-phase GEMM, v3 (R5/R7-measured best: 45.6% MfmaUtil) ==========
// Schedule is a MEASURED LOCAL OPTIMUM — R6 counted-lgkm: −9%; R8 deep-slack: −5%. Do not
// perturb without within-probe A/B. Epilogue MODEs:
//   1 = split-K fp32 partials via blockIdx.z (O0/O1 + k_add2_f32 reduce)
//   4 = fused qkvg (N=12288 over [WqT|WkT|WvT|WgT]): n0 [0,2k)=q-RoPE, [2k,4k)=k-RoPE,
//       [4k,8k)=vS-build, [8k,12k)=g plain bf16. Outputs O0=qb O1=kb O2=vS O3=gb.
#define BARX() asm volatile("s_barrier" ::: "memory")
#define LGKM0() { asm volatile("s_waitcnt lgkmcnt(0)" ::: "memory"); __builtin_amdgcn_sched_barrier(0); }
#define VMW4() asm volatile("s_waitcnt vmcnt(4)" ::: "memory")
#define VMW0() asm volatile("s_waitcnt vmcnt(0)" ::: "memory")
#define PRIO1 __builtin_amdgcn_s_setprio(1)
#define PRIO0 __builtin_amdgcn_s_setprio(0)

#define QUADQ(MB, NB)                                                              \
  { _Pragma("unroll") for (int kk_ = 0; kk_ < 2; ++kk_)                            \
    _Pragma("unroll") for (int mf_ = 0; mf_ < 4; ++mf_)                            \
    _Pragma("unroll") for (int nf_ = 0; nf_ < 2; ++nf_)                            \
      acc[(MB) + mf_][(NB) + nf_] = __builtin_amdgcn_mfma_f32_16x16x32_bf16(       \
          ar[(MB) + mf_][kk_], br[(NB) + nf_][kk_],                                \
          acc[(MB) + mf_][(NB) + nf_], 0, 0, 0); }

template <int MODE>
__global__ __launch_bounds__(512, 2) void k_gemm8(const bf16* __restrict__ A, const bf16* __restrict__ BT,
                                                  void* __restrict__ O0, void* __restrict__ O1,
                                                  void* __restrict__ O2, void* __restrict__ O3,
                                                  int nsplit, int M, int Ntot, int Kloop, int Kstride) {
  extern __shared__ char lds[];
  const int tid = threadIdx.x;
  const int lane = tid & 63;
  const int w = tid >> 6;        // 0..7
  const int wr = w >> 2;         // 0..1 (M half)
  const int wc = w & 3;          // 0..3 (N quarter)
  const int quad = lane >> 4, c16 = lane & 15;
  const int m0 = blockIdx.y * 256, n0 = blockIdx.x * 256;
  const int ks = blockIdx.z;

  const bf16* Ab = A + (size_t)ks * Kloop;
  const bf16* Bb = BT + (size_t)ks * Kloop;

  const int srow = (w << 4) | (lane >> 3);
  const int gsw = (((lane & 7) ^ (lane >> 3)) << 4);   // inverse-swizzled source granule
  const size_t rowBytes = (size_t)Kstride * 2;
  const char* aS = (const char*)(Ab + (size_t)(m0 + srow) * Kstride) + gsw;
  const char* bS = (const char*)(Bb + (size_t)(n0 + srow) * Kstride) + gsw;

  auto stage = [&](int matB, int buf, int h, int t) {
    const char* base = (matB ? bS : aS) + (size_t)h * 128 * rowBytes + (size_t)t * 128;
    char* ldst = lds + buf * 65536 + matB * 32768 + h * 16384 + w * 2048;
    gload_lds16(base, ldst);
    gload_lds16(base + 8 * rowBytes, ldst + 1024);
  };
  auto ldA = [&](int buf, int mf, int kk) -> bf16x8 {
    int row = wr * 128 + mf * 16 + c16;
    return *(const bf16x8*)(lds + buf * 65536 + row * 128 + ((((kk << 2) | quad) ^ (c16 & 7)) << 4));
  };
  auto ldB = [&](int buf, int nf, int kk) -> bf16x8 {
    int row = wc * 64 + nf * 16 + c16;
    return *(const bf16x8*)(lds + buf * 65536 + 32768 + row * 128 + ((((kk << 2) | quad) ^ (c16 & 7)) << 4));
  };

  f32x4 acc[8][4];
  const f32x4 fz = {0.f, 0.f, 0.f, 0.f};
#pragma unroll
  for (int i = 0; i < 8; i++)
#pragma unroll
    for (int j = 0; j < 4; j++) acc[i][j] = fz;
  bf16x8 ar[8][2], br[4][2];

  const int nT = Kloop >> 6;
  const int nIter = nT >> 1;

  // prologue: tile0 full + tile1 A -> 12 loads; vmcnt(4) leaves t1.A in flight
  stage(0, 0, 0, 0); stage(0, 0, 1, 0);
  stage(1, 0, 0, 0); stage(1, 0, 1, 0);
  stage(0, 1, 0, 1); stage(0, 1, 1, 1);
  VMW4();
  BARX();

  for (int it = 0; it < nIter; ++it) {
    const int t = it * 2;
    const bool last = (it == nIter - 1);
    // ---- ph1: ds A0-3 + B01 (buf0); stage (t+1)B0; Q00 ----
#pragma unroll
    for (int mf = 0; mf < 4; ++mf) { ar[mf][0] = ldA(0, mf, 0); ar[mf][1] = ldA(0, mf, 1); }
#pragma unroll
    for (int nf = 0; nf < 2; ++nf) { br[nf][0] = ldB(0, nf, 0); br[nf][1] = ldB(0, nf, 1); }
    stage(1, 1, 0, t + 1);
    BARX(); LGKM0();
    PRIO1; QUADQ(0, 0); PRIO0;
    BARX();
    // ---- ph2: ds A4-7 (buf0); stage (t+1)B1; Q10 ----
#pragma unroll
    for (int mf = 4; mf < 8; ++mf) { ar[mf][0] = ldA(0, mf, 0); ar[mf][1] = ldA(0, mf, 1); }
    stage(1, 1, 1, t + 1);
    BARX(); LGKM0();
    PRIO1; QUADQ(4, 0); PRIO0;
    BARX();
    // ---- ph3: ds B23 (buf0); stage (t+2)A0; Q01 ----
#pragma unroll
    for (int nf = 2; nf < 4; ++nf) { br[nf][0] = ldB(0, nf, 0); br[nf][1] = ldB(0, nf, 1); }
    if (!last) stage(0, 0, 0, t + 2);
    BARX(); LGKM0();
    PRIO1; QUADQ(0, 2); PRIO0;
    BARX();
    // ---- ph4: stage (t+2)A1; Q11; vmcnt(4) -> tile t+1 landed ----
    if (!last) stage(0, 0, 1, t + 2);
    BARX();
    PRIO1; QUADQ(4, 2); PRIO0;
    if (!last) { VMW4(); } else { VMW0(); }
    BARX();
    // ---- ph5: ds A0-3 + B01 (buf1); stage (t+2)B0; Q00 ----
#pragma unroll
    for (int mf = 0; mf < 4; ++mf) { ar[mf][0] = ldA(1, mf, 0); ar[mf][1] = ldA(1, mf, 1); }
#pragma unroll
    for (int nf = 0; nf < 2; ++nf) { br[nf][0] = ldB(1, nf, 0); br[nf][1] = ldB(1, nf, 1); }
    if (!last) stage(1, 0, 0, t + 2);
    BARX(); LGKM0();
    PRIO1; QUADQ(0, 0); PRIO0;
    BARX();
    // ---- ph6: ds A4-7 (buf1); stage (t+2)B1; Q10 ----
#pragma unroll
    for (int mf = 4; mf < 8; ++mf) { ar[mf][0] = ldA(1, mf, 0); ar[mf][1] = ldA(1, mf, 1); }
    if (!last) stage(1, 0, 1, t + 2);
    BARX(); LGKM0();
    PRIO1; QUADQ(4, 0); PRIO0;
    BARX();
    // ---- ph7: ds B23 (buf1); stage (t+3)A0; Q01 ----
#pragma unroll
    for (int nf = 2; nf < 4; ++nf) { br[nf][0] = ldB(1, nf, 0); br[nf][1] = ldB(1, nf, 1); }
    if (!last) stage(0, 1, 0, t + 3);
    BARX(); LGKM0();
    PRIO1; QUADQ(0, 2); PRIO0;
    BARX();
    // ---- ph8: stage (t+3)A1; Q11; vmcnt(4) ----
    if (!last) stage(0, 1, 1, t + 3);
    BARX();
    PRIO1; QUADQ(4, 2); PRIO0;
    if (!last) VMW4();
    BARX();
  }

  if (MODE == 4) {
    if (n0 < 4096) {
      // ---- RoPE epilogue (q: n0<2048, k: 2048..4095) ----
      __syncthreads();
      ushort_t* tile = (ushort_t*)lds;
#pragma unroll
      for (int mf = 0; mf < 8; ++mf)
#pragma unroll
        for (int nf = 0; nf < 4; ++nf)
#pragma unroll
          for (int rr = 0; rr < 4; ++rr) {
            int row = wr * 128 + mf * 16 + quad * 4 + rr;
            int col = wc * 64 + nf * 16 + c16;
            tile[row * 256 + col] = f2bf_raw(acc[mf][nf][rr]);
          }
      __syncthreads();
      const bool qside = (n0 < 2048);
      bf16* Ob = (bf16*)(qside ? O0 : O1);
      const float scale = qside ? 0.0625f : 1.0f;
      const int h = (qside ? n0 : n0 - 2048) >> 8;
#pragma unroll
      for (int j = 0; j < 8; ++j) {
        int u = j * 512 + tid;
        int row = u >> 4;
        int ch = u & 15;
        const ushort_t* lp = tile + row * 256 + ch * 8;
        us8 lo = *(const us8*)lp;
        us8 hi = *(const us8*)(lp + 128);
        int m = m0 + row;
        float tf = (float)(m & (Tn - 1));
        us8 olo, ohi;
#pragma unroll
        for (int e = 0; e < 8; ++e) {
          int i = ch * 8 + e;
          float inv = exp2f(-(float)i * (13.287712379549449f / 128.0f));
          float ang = tf * inv;
          float s, c;
          sincosf(ang, &s, &c);
          float x1 = bf2f_raw(lo[e]);
          float x2 = bf2f_raw(hi[e]);
          olo[e] = f2bf_raw((x1 * c - x2 * s) * scale);
          ohi[e] = f2bf_raw((x2 * c + x1 * s) * scale);
        }
        ushort_t* dst = (ushort_t*)Ob + ((size_t)m * NH + h) * DKk + ch * 8;
        *(us8*)dst = olo;
        *(us8*)(dst + 128) = ohi;
      }
    } else if (n0 < 8192) {
      // ---- vS-build epilogue: unit (bh,kt,chunk,dv)[jj] = v[kt*32+chunk*8+jj][dv] ----
      __syncthreads();
      ushort_t* tile = (ushort_t*)lds;
#pragma unroll
      for (int mf = 0; mf < 8; ++mf)
#pragma unroll
        for (int nf = 0; nf < 4; ++nf)
#pragma unroll
          for (int rr = 0; rr < 4; ++rr) {
            int row = wr * 128 + mf * 16 + quad * 4 + rr;
            int col = wc * 64 + nf * 16 + c16;
            tile[row * 256 + col] = f2bf_raw(acc[mf][nf][rr]);
          }
      __syncthreads();
      const int nv = n0 - 4096;
      const int b = m0 >> 11;
      const int kt0 = (m0 & 2047) >> 5;
      const int h = nv >> 9;
      const int dv0 = nv & 511;
      const int bh = b * 8 + h;
      ushort_t* vSo = (ushort_t*)O2;
#pragma unroll
      for (int uu = 0; uu < 16; ++uu) {
        int u = uu * 512 + tid;
        int ktl = u >> 10;
        int chunk = (u >> 8) & 3;
        int dvl = u & 255;
        us8 o;
#pragma unroll
        for (int jj = 0; jj < 8; ++jj)
          o[jj] = tile[(ktl * 32 + chunk * 8 + jj) * 256 + dvl];
        *(us8*)(vSo + ((size_t)(bh * 64 + kt0 + ktl) * 2048 + chunk * 512 + (dv0 + dvl)) * 8) = o;
      }
    } else {
      // ---- g plain bf16: gb[4096][4096] ----
      bf16* Ob = (bf16*)O3;
      const int nc0 = n0 - 8192;
#pragma unroll
      for (int mf = 0; mf < 8; ++mf)
#pragma unroll
        for (int nf = 0; nf < 4; ++nf)
#pragma unroll
          for (int rr = 0; rr < 4; ++rr) {
            int m = m0 + wr * 128 + mf * 16 + quad * 4 + rr;
            int n = nc0 + wc * 64 + nf * 16 + c16;
            Ob[(size_t)m * 4096 + n] = __float2bfloat16(acc[mf][nf][rr]);
          }
    }
  } else if (MODE == 1) {
    // split-K fp32 partial: z selects buffer, full N width
    float* Ob = (float*)(ks ? O1 : O0);
#pragma unroll
    for (int mf = 0; mf < 8; ++mf)
#pragma unroll
      for (int nf = 0; nf < 4; ++nf)
#pragma unroll
        for (int rr = 0; rr < 4; ++rr) {
          int m = m0 + wr * 128 + mf * 16 + quad * 4 + rr;
          int n = n0 + wc * 64 + nf * 16 + c16;
          Ob[(size_t)m * Ntot + n] = acc[mf][nf][rr];
        }
  }
}

// ---------------- Retention v4 (R5/R7-measured best): rotated loop {PV(t-1); S(t)} ----------------
// K-dbuf + V-sbuf + P-dbuf, LDS 76.8KB -> 2 blocks/CU + counted-vmcnt pipelining.
// Ledger verified in R4/R5. (v5 swapped-S + shfl redistribute regressed in R6 — do not reapply.)
__global__ __launch_bounds__(256, 2) void k_retention(const bf16* __restrict__ q, const bf16* __restrict__ k,
                                                      const char* __restrict__ vS, const bf16* __restrict__ g,
                                                      const float* __restrict__ gnw, bf16* __restrict__ X) {
  extern __shared__ char smem[];
  ushort_t* p_lds_base = (ushort_t*)(smem + 65536);
  float* red = (float*)(smem + 75776);
  bf16* o_lds = (bf16*)smem;   // epilogue alias (64KB)

  const int tid = threadIdx.x;
  const int l = tid & 63, w = tid >> 6;
  const int quad = l >> 4, c16 = l & 15;

  const int bid = blockIdx.x;
  const int u = (bid & 255) >> 4;
  const int qt = (bid < 256) ? (31 - u) : u;   // heavy half then light half
  const int bh = bid & 15;
  const int b = bh >> 3, h = bh & 7;
  const int q0 = qt * 64;

  bf16x8 qf[8];
  {
    const bf16* qrow = q + ((size_t)(b * Tn + q0 + w * 16 + c16) * NH + h) * DKk + quad * 8;
#pragma unroll
    for (int c = 0; c < 8; c++) qf[c] = *(const bf16x8*)(qrow + c * 32);
  }

  const float log2g = log2f(1.0f - exp2f(-5.0f - (float)h));

  f32x4 acc[4][8];
  const f32x4 fz = {0.f, 0.f, 0.f, 0.f};
#pragma unroll
  for (int rt = 0; rt < 4; rt++)
#pragma unroll
    for (int n = 0; n < 8; n++) acc[rt][n] = fz;

  const int ktmax = 2 * qt + 1;
  const float Dcut = 30.0f / (-log2g);
  int kt0 = (int)fmaxf(0.0f, floorf(((float)q0 - Dcut) * (1.0f / 32.0f)));

  const char* vS_tilebase = vS + (size_t)(bh * 64) * 32768;

  auto stageK = [&](int kt) {
    const int pb = (kt - kt0) & 1;
#pragma unroll
    for (int i = 0; i < 4; i++) {
      int instr = w * 4 + i;
      int j = instr * 2 + (l >> 5);
      int cg = (l & 31) ^ (j & 7);
      const char* gp = (const char*)(k + ((size_t)(b * Tn + kt * 32 + j) * NH + h) * DKk) + cg * 16;
      gload_lds16(gp, smem + pb * 16384 + instr * 1024);
    }
  };
  auto stageV = [&](int kt) {
#pragma unroll
    for (int i = 0; i < 8; i++) {
      int instr = w * 8 + i;
      const char* gp = vS_tilebase + (size_t)kt * 32768 + instr * 1024 + l * 16;
      gload_lds16(gp, smem + 32768 + instr * 1024);
    }
  };

  auto S_phase = [&](int kt) {
    const int pb = (kt - kt0) & 1;
    f32x4 sacc[2] = {fz, fz};
#pragma unroll
    for (int jt = 0; jt < 2; jt++)
#pragma unroll
      for (int c = 0; c < 8; c++) {
        const char* kp = smem + pb * 16384 + (jt * 16 + c16) * 512 + (((c * 4 + quad) ^ (c16 & 7)) * 16);
        bf16x8 bfrag = *(const bf16x8*)kp;
        sacc[jt] = __builtin_amdgcn_mfma_f32_16x16x32_bf16(qf[c], bfrag, sacc[jt], 0, 0, 0);
      }
    ushort_t* pbuf = p_lds_base + pb * 2560;
#pragma unroll
    for (int jt = 0; jt < 2; jt++)
#pragma unroll
      for (int r = 0; r < 4; r++) {
        int ig = q0 + w * 16 + quad * 4 + r;
        int jg = kt * 32 + jt * 16 + c16;
        int d = ig - jg;
        float val = (d >= 0) ? sacc[jt][r] * exp2f(log2g * (float)d) : 0.0f;
        pbuf[(w * 16 + quad * 4 + r) * 40 + jt * 16 + c16] = f2bf_raw(val);
      }
  };

  auto PV_phase = [&](int kt) {
    const int pb = (kt - kt0) & 1;
    const char* pbuf = (const char*)(p_lds_base + pb * 2560);
    bf16x8 pa[4];
#pragma unroll
    for (int rt = 0; rt < 4; rt++)
      pa[rt] = *(const bf16x8*)(pbuf + (rt * 16 + c16) * 80 + quad * 16);
    const char* v_lds = smem + 32768;
#pragma unroll
    for (int n = 0; n < 8; n++) {
      bf16x8 bv = *(const bf16x8*)(v_lds + quad * 8192 + (w * 128 + n * 16 + c16) * 16);
#pragma unroll
      for (int rt = 0; rt < 4; rt++)
        acc[rt][n] = __builtin_amdgcn_mfma_f32_16x16x32_bf16(pa[rt], bv, acc[rt][n], 0, 0, 0);
    }
  };

#define SBARR() { __builtin_amdgcn_sched_barrier(0); __builtin_amdgcn_s_barrier(); }
#define WLGKM0() { asm volatile("s_waitcnt lgkmcnt(0)" ::: "memory"); }

  // ---- peeled first iteration (S-only) ----
  stageK(kt0);                                        // out: K(kt0)(4)  [+qf(8) older]
  stageV(kt0);                                        // out: +V(kt0)(8)
  asm volatile("s_waitcnt vmcnt(8)" ::: "memory");    // drains qf + K(kt0); V(kt0) flies
  SBARR();
  S_phase(kt0);
  if (kt0 + 1 <= ktmax) stageK(kt0 + 1);              // out: V(kt0)(8), K(kt0+1)(4)
  WLGKM0(); SBARR();

  // ---- main loop ----
  for (int kt = kt0 + 1; kt <= ktmax; ++kt) {
    asm volatile("s_waitcnt vmcnt(4)" ::: "memory");  // V(kt-1) landed; K(kt) flies
    SBARR();
    PV_phase(kt - 1);
    WLGKM0(); SBARR();                                // V buf + p[kt-1] free
    stageV(kt);                                       // out: K(kt)(4), V(kt)(8)
    asm volatile("s_waitcnt vmcnt(8)" ::: "memory");  // K(kt) landed; V(kt) flies
    SBARR();
    S_phase(kt);
    if (kt + 1 <= ktmax) stageK(kt + 1);              // out: V(kt)(8), K(kt+1)(4)
    WLGKM0(); SBARR();                                // p[kt] visible
  }

  // ---- epilogue PV(ktmax) ----
  asm volatile("s_waitcnt vmcnt(0)" ::: "memory");
  SBARR();
  PV_phase(ktmax);

  // RMS: wave has 128-dv partial for all 64 rows -> cross-wave combine via red
  __syncthreads();
#pragma unroll
  for (int rt = 0; rt < 4; rt++)
#pragma unroll
    for (int r = 0; r < 4; r++) {
      float s = 0.f;
#pragma unroll
      for (int n = 0; n < 8; n++) { float v = acc[rt][n][r]; s += v * v; }
      s += __shfl_xor(s, 1);
      s += __shfl_xor(s, 2);
      s += __shfl_xor(s, 4);
      s += __shfl_xor(s, 8);
      if (c16 == 0) red[(rt * 16 + quad * 4 + r) * 4 + w] = s;
    }
  __syncthreads();
  float ss[4][4];
#pragma unroll
  for (int rt = 0; rt < 4; rt++)
#pragma unroll
    for (int r = 0; r < 4; r++) {
      int row = rt * 16 + quad * 4 + r;
      float tot = red[row * 4] + red[row * 4 + 1] + red[row * 4 + 2] + red[row * 4 + 3];
      ss[rt][r] = rsqrtf(tot * (1.0f / DVv) + EPSf);
    }
  __syncthreads();

#pragma unroll
  for (int n = 0; n < 8; n++) {
    int col = w * 128 + n * 16 + c16;
    float gw = gnw[col];
#pragma unroll
    for (int rt = 0; rt < 4; rt++)
#pragma unroll
      for (int r = 0; r < 4; r++) {
        int row = rt * 16 + quad * 4 + r;
        o_lds[row * 512 + col] = __float2bfloat16(acc[rt][n][r] * ss[rt][r] * gw);
      }
  }
  __syncthreads();

#pragma unroll
  for (int it = 0; it < 16; it++) {
    int cid = it * 256 + tid;
    int row = cid >> 6;
    int cp = (cid & 63) * 8;
    const ushort_t* gp = (const ushort_t*)g + ((size_t)(b * Tn + q0 + row) * NH + h) * DVv + cp;
    us8 gv = *(const us8*)gp;
    us8 ov;
#pragma unroll
    for (int e = 0; e < 8; e++) {
      float gf = bf2f_raw(gv[e]);
      float gate = gf / (1.0f + expf(-gf));
      float of = __bfloat162float(o_lds[row * 512 + cp + e]);
      ov[e] = f2bf_raw(of * gate);
    }
    *(us8*)((ushort_t*)X + ((size_t)(b * Tn + q0 + row) * NH + h) * DVv + cp) = ov;
  }
}

extern "C" void kernel_launch(void* const* d_in, const int* in_sizes, int n_in,
                              void* d_out, int out_size, void* d_ws, size_t ws_size,
                              hipStream_t stream) {
  const float* hs  = (const float*)d_in[0];
  const float* Wq  = (const float*)d_in[1];
  const float* Wk  = (const float*)d_in[2];
  const float* Wv  = (const float*)d_in[3];
  const float* Wg  = (const float*)d_in[4];
  const float* Wo  = (const float*)d_in[5];
  const float* gnw = (const float*)d_in[6];
  float* out = (float*)d_out;
  char* ws = (char*)d_ws;

  // Workspace map (audited R11/R12):
  //   hsb 0..16MB | WqT 16..24 | WkT 24..32 | WvT 32..48 | WgT 48..64  (B = [WqT|WkT|WvT|WgT]
  //   contiguous [12288][2048] for fused qkvg GEMM)
  //   qb 64..80 | kb 80..96 | vSb 96..128 | gb 128..160
  //   WoT 160..176 (fresh region — prep writes it up front, read at out-proj)
  //   Xb 0..32 (alias hsb/WqT/WkT, retention out) | p0 48..80 (alias WgT+qb) | p1 80..112
  bf16* hsb = (bf16*)(ws);
  bf16* WqT = (bf16*)(ws + 16777216);
  bf16* WkT = (bf16*)(ws + 25165824);
  bf16* WvT = (bf16*)(ws + 33554432);
  bf16* WgT = (bf16*)(ws + 50331648);
  bf16* qb  = (bf16*)(ws + 67108864);
  bf16* kb  = (bf16*)(ws + 83886080);
  char* vSb = ws + 100663296;
  bf16* gb  = (bf16*)(ws + 134217728);
  bf16* WoT = (bf16*)(ws + 167772160);
  bf16* Xb  = (bf16*)ws;
  float* p0 = (float*)(ws + 50331648);
  float* p1 = (float*)(ws + 83886080);

  static bool attr_done = false;
  if (!attr_done) {
    hipFuncSetAttribute((const void*)k_gemm8<1>, hipFuncAttributeMaxDynamicSharedMemorySize, 131072);
    hipFuncSetAttribute((const void*)k_gemm8<4>, hipFuncAttributeMaxDynamicSharedMemorySize, 131072);
    hipFuncSetAttribute((const void*)k_retention, hipFuncAttributeMaxDynamicSharedMemorySize, 76800);
    attr_done = true;
  }

  // 1) prep: hs cast + all 5 weight transposes in one launch
  k_prep<<<16384, 256, 0, stream>>>(hs, (ushort4*)hsb, Wq, Wk, Wv, Wg, Wo,
                                    WqT, WkT, WvT, WgT, WoT);
  // 2) fused qkvg GEMM (N=12288): q->qb (RoPE, 0.0625), k->kb (RoPE), v->vSb (vS layout), g->gb
  k_gemm8<4><<<dim3(48, 16), 512, 131072, stream>>>(hsb, WqT, qb, kb, vSb, gb,
                                                    0, 4096, 12288, 2048, 2048);
  // 3) retention
  k_retention<<<512, 256, 76800, stream>>>(qb, kb, vSb, gb, gnw, Xb);
  // 4) out-proj split-K=2 (256 blocks, full GPU), fp32 partials
  k_gemm8<1><<<dim3(8, 16, 2), 512, 131072, stream>>>(Xb, WoT, p0, p1, nullptr, nullptr,
                                                      2048, 4096, 2048, 2048, 4096);
  // 5) reduce
  k_add2_f32<<<8192, 256, 0, stream>>>((const float4*)p0, (const float4*)p1, (float4*)out, 2097152);
}